// Round 3
// baseline (343.374 us; speedup 1.0000x reference)
//
#include <hip/hip_runtime.h>
#include <cstdint>

typedef unsigned short u16;
typedef short bf16x8 __attribute__((ext_vector_type(8)));
typedef float f32x4 __attribute__((ext_vector_type(4)));
typedef float f32x16 __attribute__((ext_vector_type(16)));
typedef unsigned int u32x2 __attribute__((ext_vector_type(2)));
typedef unsigned int u32x4 __attribute__((ext_vector_type(4)));

#define NB 4
#define SEQ 2048
#define DMODEL 1024
#define NHEADS 16
#define DHEAD 64
#define BHTOT (NB*NHEADS)   // 64
#define MROWS (NB*SEQ)      // 8192

__device__ __forceinline__ float bf2f(u16 u){
  union { unsigned int i; float f; } x; x.i = ((unsigned int)u)<<16; return x.f;
}
__device__ __forceinline__ u16 f2bf(float f){
  union { float f; unsigned int i; } x; x.f = f;
  unsigned int r = x.i + 0x7fffu + ((x.i>>16)&1u);
  return (u16)(r>>16);
}

typedef const __attribute__((address_space(1))) unsigned int* gas_t;
typedef __attribute__((address_space(3))) unsigned int* las_t;
__device__ __forceinline__ void async_cp16(const void* g, void* l){
  __builtin_amdgcn_global_load_lds((gas_t)g, (las_t)l, 16, 0, 0);
}

// permlane32_swap: rows 32-63 of a exchange with rows 0-31 of b
__device__ __forceinline__ void plswap(unsigned int &a, unsigned int &b){
#if __has_builtin(__builtin_amdgcn_permlane32_swap)
  u32x2 r = __builtin_amdgcn_permlane32_swap(a, b, false, false);
  a = r[0]; b = r[1];
#else
  asm("v_permlane32_swap_b32 %0, %1" : "+v"(a), "+v"(b));
#endif
}

// ---------------- fp32 -> bf16 cast for BOTH weights (one launch) ----------------
__global__ __launch_bounds__(256) void cast2_kernel(const float* __restrict__ wa, u16* __restrict__ oa,
    const float* __restrict__ wb, u16* __restrict__ ob, int na4){
  int i = blockIdx.x*256 + threadIdx.x;
  const float* src; u16* dst; int j;
  if(i < na4){ src = wa; dst = oa; j = i; }
  else       { src = wb; dst = ob; j = i - na4; }
  float4 v = ((const float4*)src)[j];
  ushort4 o;
  o.x=f2bf(v.x); o.y=f2bf(v.y); o.z=f2bf(v.z); o.w=f2bf(v.w);
  ((ushort4*)dst)[j] = o;
}

// ---------------- LayerNorm: x fp32 -> h bf16 (f32 stats) ----------------
__global__ __launch_bounds__(256) void ln_kernel(const float* __restrict__ x, u16* __restrict__ h){
  int row = blockIdx.x;
  const float* xr = x + (size_t)row*DMODEL;
  u16* hr = h + (size_t)row*DMODEL;
  int t = threadIdx.x;
  float4 v = ((const float4*)xr)[t];
  float f0=v.x, f1=v.y, f2=v.z, f3=v.w;
  float s = f0+f1+f2+f3;
  float q = f0*f0+f1*f1+f2*f2+f3*f3;
  #pragma unroll
  for(int off=32; off; off>>=1){ s += __shfl_xor(s, off); q += __shfl_xor(q, off); }
  __shared__ float ss[4], sq[4];
  int wv = t>>6, lane = t&63;
  if(lane==0){ ss[wv]=s; sq[wv]=q; }
  __syncthreads();
  s = ss[0]+ss[1]+ss[2]+ss[3];
  q = sq[0]+sq[1]+sq[2]+sq[3];
  float mu  = s * (1.0f/DMODEL);
  float var = q * (1.0f/DMODEL) - mu*mu;
  float rs  = rsqrtf(var + 1e-8f);
  ushort4 o;
  o.x=f2bf((f0-mu)*rs); o.y=f2bf((f1-mu)*rs); o.z=f2bf((f2-mu)*rs); o.w=f2bf((f3-mu)*rs);
  ((ushort4*)hr)[t] = o;
}

// ---------------- GEMM: C[m,n] = sum_k A[m,k]*Bm[n,k], bf16 MFMA ----------------
#define BM 128
#define BN 128
#define BK 32

template<int MODE>
__global__ __launch_bounds__(256) void gemm_bt(const u16* __restrict__ A, const u16* __restrict__ Bm,
    u16* __restrict__ Qb, u16* __restrict__ Kb, u16* __restrict__ Vtb, float* __restrict__ outf,
    int M, int N, int K){
  __shared__ u16 As[BM*BK];
  __shared__ u16 Bs[BN*BK];
  int t = threadIdx.x;
  int lane = t&63, wv = t>>6;
  int c = lane&15, g = lane>>4;
  int wm = wv>>1, wn = wv&1;
  int m0 = blockIdx.y*BM, n0 = blockIdx.x*BN;
  f32x4 acc[4][4] = {};
  for(int k0=0;k0<K;k0+=BK){
    __syncthreads();
    #pragma unroll
    for(int i=0;i<2;i++){
      int e = t*8 + i*2048;
      int r = e>>5, col = e&31;
      async_cp16(&A [(size_t)(m0+r)*K + k0 + col], &As[e]);
      async_cp16(&Bm[(size_t)(n0+r)*K + k0 + col], &Bs[e]);
    }
    __syncthreads();
    bf16x8 af[4], bfr[4];
    #pragma unroll
    for(int i=0;i<4;i++){
      af[i]  = *(const bf16x8*)(&As[(wm*64 + i*16 + c)*BK + g*8]);
      bfr[i] = *(const bf16x8*)(&Bs[(wn*64 + i*16 + c)*BK + g*8]);
    }
    #pragma unroll
    for(int mi=0;mi<4;mi++)
      #pragma unroll
      for(int ni=0;ni<4;ni++)
        acc[mi][ni] = __builtin_amdgcn_mfma_f32_16x16x32_bf16(af[mi], bfr[ni], acc[mi][ni], 0,0,0);
  }
  if(MODE==1){
    #pragma unroll
    for(int mi=0;mi<4;mi++){
      int mrow = m0 + wm*64 + mi*16 + g*4;
      #pragma unroll
      for(int ni=0;ni<4;ni++){
        int ncol = n0 + wn*64 + ni*16 + c;
        #pragma unroll
        for(int r=0;r<4;r++)
          outf[(size_t)(mrow+r)*N + ncol] = acc[mi][ni][r];
      }
    }
  } else {
    #pragma unroll
    for(int ni=0;ni<4;ni++){
      int n = n0 + wn*64 + ni*16 + c;
      int sel = n>>10, head = (n>>6)&15, d = n&63;
      #pragma unroll
      for(int mi=0;mi<4;mi++){
        int m = m0 + wm*64 + mi*16 + g*4;
        int b = m>>11, l = m&(SEQ-1);
        if(sel<2){
          u16* dst = (sel==0?Qb:Kb) + ((size_t)((b*NHEADS+head)*SEQ + l))*DHEAD + d;
          #pragma unroll
          for(int r=0;r<4;r++) dst[(size_t)r*DHEAD] = f2bf(acc[mi][ni][r]);
        } else {
          ushort4 pk;
          pk.x=f2bf(acc[mi][ni][0]); pk.y=f2bf(acc[mi][ni][1]);
          pk.z=f2bf(acc[mi][ni][2]); pk.w=f2bf(acc[mi][ni][3]);
          *(ushort4*)(&Vtb[((size_t)((b*NHEADS+head)*DHEAD + d))*SEQ + l]) = pk;
        }
      }
    }
  }
}

// ---------------- RoPE: one thread per (l,j), sincos once, loop over bh ----------------
// Q additionally pre-scaled by scale*log2(e) so attn's softmax is a bare exp2.
#define SC2 0.180336879f   // 0.125 * log2(e)
__global__ __launch_bounds__(256) void rope_kernel(u16* __restrict__ Q, u16* __restrict__ Kb){
  int tid = blockIdx.x*256 + threadIdx.x;   // SEQ*32 threads
  int j = tid&31, l = tid>>5;
  float inv = exp2f(-(float)j * (13.28771237954945f/32.0f)); // 10000^(-j/32)
  float sn, cs;
  sincosf((float)l*inv, &sn, &cs);
  size_t base = (size_t)l*DHEAD + 2*j;
  #pragma unroll 4
  for(int bh=0; bh<BHTOT; bh++){
    size_t off = base + (size_t)bh*SEQ*DHEAD;
    ushort2 q2 = *(ushort2*)(&Q[off]);
    float x1=bf2f(q2.x), x2=bf2f(q2.y);
    ushort2 o;
    o.x = f2bf((x1*cs - x2*sn)*SC2); o.y = f2bf((x1*sn + x2*cs)*SC2);
    *(ushort2*)(&Q[off]) = o;
    ushort2 k2 = *(ushort2*)(&Kb[off]);
    x1=bf2f(k2.x); x2=bf2f(k2.y);
    o.x = f2bf(x1*cs - x2*sn); o.y = f2bf(x1*sn + x2*cs);
    *(ushort2*)(&Kb[off]) = o;
  }
}

// ---------------- Flash attention: 32x32 swapped-QK^T, in-register P ----------------
// Block = 128 threads (2 waves) owns one 32-row q strip s; causal range s+1 KV
// tiles split between the waves; exact add-merge (no online max; scores bounded,
// Q pre-scaled so P = exp2(S)).
// Per tile: S^T = mfma32x32x16(K, Q)  -> lane holds P[q=lane&31][k=(reg&3)+8*(reg>>2)+4*(lane>>5)]
// P -> bf16 PV A-frags entirely in registers: 8x v_cvt_pk_bf16_f32 + 4x permlane32_swap
// (T12). No P LDS round-trip; LDS only for the 2-wave merge epilogue.
// XCD-pinned block remap (T1): all 64 strips of a bh land on XCD bh>>3
// (assumes linear workgroup id round-robins XCDs). K+Vt working set per XCD
// = 8 bh x 512 KB = 4 MiB -> hot low-k tiles stay L2-resident instead of
// every XCD streaming all 48 MB through the L2-miss path.
#define OSTR 66   // Osum row stride (floats)

#define LOADK32(TILE, KF) { int tb_=(TILE)*32; \
  _Pragma("unroll") for(int dk_=0;dk_<4;dk_++) \
    KF[dk_] = *(const bf16x8*)(&Kp[(size_t)(tb_ + c32)*DHEAD + dk_*16 + h8]); }

#define LOADV32(TILE, VF) { int tb_=(TILE)*32; \
  _Pragma("unroll") for(int dt_=0;dt_<2;dt_++) \
    _Pragma("unroll") for(int ks_=0;ks_<2;ks_++) \
      VF[dt_][ks_] = *(const bf16x8*)(&Vp[(size_t)(dt_*32 + c32)*SEQ + tb_ + ks_*16 + h8]); }

#define QKS32(KF) { \
  f32x16 z_ = {}; \
  z_ = __builtin_amdgcn_mfma_f32_32x32x16_bf16(KF[0], qf[0], z_, 0,0,0); \
  z_ = __builtin_amdgcn_mfma_f32_32x32x16_bf16(KF[1], qf[1], z_, 0,0,0); \
  z_ = __builtin_amdgcn_mfma_f32_32x32x16_bf16(KF[2], qf[2], z_, 0,0,0); \
  z_ = __builtin_amdgcn_mfma_f32_32x32x16_bf16(KF[3], qf[3], z_, 0,0,0); \
  sc = z_; }

// pk_[j] = packed bf16 of P for regs (2j, 2j+1); after the two swaps per half,
// pk words are exactly the PV A-frag words (k = 8*(lane>>5)+elem).
#define EXPPACK(DIAG) { \
  unsigned int pk_[8]; \
  _Pragma("unroll") for(int j_=0;j_<8;j_++){ \
    float a_ = exp2f(sc[2*j_]); \
    float b_ = exp2f(sc[2*j_+1]); \
    if(DIAG){ \
      int k0_ = ((2*j_)&3)   + 8*((2*j_)>>2)   + 4*hl; \
      int k1_ = ((2*j_+1)&3) + 8*((2*j_+1)>>2) + 4*hl; \
      a_ = (k0_ <= c32) ? a_ : 0.f; \
      b_ = (k1_ <= c32) ? b_ : 0.f; } \
    asm("v_cvt_pk_bf16_f32 %0, %1, %2" : "=v"(pk_[j_]) : "v"(a_), "v"(b_)); } \
  plswap(pk_[0], pk_[2]); \
  plswap(pk_[1], pk_[3]); \
  plswap(pk_[4], pk_[6]); \
  plswap(pk_[5], pk_[7]); \
  u32x4 wa_ = { pk_[0], pk_[1], pk_[2], pk_[3] }; \
  u32x4 wb_ = { pk_[4], pk_[5], pk_[6], pk_[7] }; \
  pa0 = __builtin_bit_cast(bf16x8, wa_); \
  pa1 = __builtin_bit_cast(bf16x8, wb_); }

#define PVM32(VF) { \
  lacc  = __builtin_amdgcn_mfma_f32_32x32x16_bf16(pa0, ones, lacc, 0,0,0); \
  lacc  = __builtin_amdgcn_mfma_f32_32x32x16_bf16(pa1, ones, lacc, 0,0,0); \
  oacc0 = __builtin_amdgcn_mfma_f32_32x32x16_bf16(pa0, VF[0][0], oacc0, 0,0,0); \
  oacc0 = __builtin_amdgcn_mfma_f32_32x32x16_bf16(pa1, VF[0][1], oacc0, 0,0,0); \
  oacc1 = __builtin_amdgcn_mfma_f32_32x32x16_bf16(pa0, VF[1][0], oacc1, 0,0,0); \
  oacc1 = __builtin_amdgcn_mfma_f32_32x32x16_bf16(pa1, VF[1][1], oacc1, 0,0,0); }

__global__ __launch_bounds__(128) void attn_kernel(const u16* __restrict__ Q, const u16* __restrict__ Kb,
    const u16* __restrict__ Vt, u16* __restrict__ O){
  __shared__ float Osum[32*OSTR];
  __shared__ float Lsum[32];
  int t = threadIdx.x, lane = t&63, w = t>>6;
  int c32 = lane&31, hl = lane>>5, h8 = hl*8;
  // XCD-pinned remap: (bx,by) -> (bh, strip-rank). XCD = bx&7 (= bh>>3).
  // rank = (by>>3)*8 + (bx>>3), early-dispatched blocks get long strips.
  int bx = blockIdx.x, by = blockIdx.y;
  int bh = ((bx & 7) << 3) + (by & 7);
  int b = bh>>4, hh = bh&15;
  int s = 63 - (((by >> 3) << 3) + (bx >> 3));   // long strips first
  int wrow = s*32;
  int nt = s+1;
  int h0 = (nt+1)>>1;
  int tbeg = w ? h0 : 0;
  int tend = w ? nt : h0;
  const u16* Qp = Q  + (size_t)bh*SEQ*DHEAD;
  const u16* Kp = Kb + (size_t)bh*SEQ*DHEAD;
  const u16* Vp = Vt + (size_t)bh*DHEAD*SEQ;
  bf16x8 ones;
  #pragma unroll
  for(int i=0;i<8;i++) ones[i] = (short)0x3f80;  // bf16 1.0

  // Q as B-frag: lane holds Q[wrow + (lane&31)][dk*16 + hl*8 .. +7]
  bf16x8 qf[4];
  #pragma unroll
  for(int dk=0;dk<4;dk++)
    qf[dk] = *(const bf16x8*)(&Qp[(size_t)(wrow + c32)*DHEAD + dk*16 + h8]);

  f32x16 oacc0 = {}, oacc1 = {}, lacc = {};
  f32x16 sc;
  bf16x8 kA[4], kB[4], vA[2][2], vB[2][2], pa0, pa1;

  int ntw = tend - tbeg;
  if(ntw > 0){
    LOADK32(tbeg, kA); LOADV32(tbeg, vA);
    int i = tbeg;
    #pragma unroll 1
    while(true){
      if(i+1 < tend){ LOADK32(i+1, kB); LOADV32(i+1, vB); }
      QKS32(kA);
      EXPPACK(i==s);
      PVM32(vA);
      i++;
      if(i >= tend) break;
      if(i+1 < tend){ LOADK32(i+1, kA); LOADV32(i+1, vA); }
      QKS32(kB);
      EXPPACK(i==s);
      PVM32(vB);
      i++;
      if(i >= tend) break;
    }
  }

  // exact merge of the two K-range partials (no max -> plain addition)
  // oacc row = (r&3)+8*(r>>2)+4*hl, col d = dt*32 + c32 ; lacc cols all equal rowsum.
  if(w==0){
    if(c32==0){
      #pragma unroll
      for(int r=0;r<16;r++) Lsum[(r&3)+8*(r>>2)+4*hl] = lacc[r];
    }
    #pragma unroll
    for(int r=0;r<16;r++){
      int row = (r&3)+8*(r>>2)+4*hl;
      Osum[row*OSTR + c32]      = oacc0[r];
      Osum[row*OSTR + 32 + c32] = oacc1[r];
    }
  }
  __syncthreads();
  if(w==1){
    #pragma unroll
    for(int r=0;r<16;r++){
      int row = (r&3)+8*(r>>2)+4*hl;
      float linv = 1.0f/(lacc[r] + Lsum[row]);
      float v0 = oacc0[r] + Osum[row*OSTR + c32];
      float v1 = oacc1[r] + Osum[row*OSTR + 32 + c32];
      size_t o = ((size_t)(b*SEQ + wrow + row))*DMODEL + hh*DHEAD;
      O[o + c32]      = f2bf(v0*linv);
      O[o + 32 + c32] = f2bf(v1*linv);
    }
  }
}

// ---------------- launch ----------------
extern "C" void kernel_launch(void* const* d_in, const int* in_sizes, int n_in,
                              void* d_out, int out_size, void* d_ws, size_t ws_size,
                              hipStream_t stream){
  const float* x    = (const float*)d_in[0];
  const float* W_in = (const float*)d_in[1];
  const float* W_o  = (const float*)d_in[2];
  u16* ws = (u16*)d_ws;
  const size_t T16 = (size_t)8*1024*1024;  // 8M bf16 elems = 16 MB per tensor
  u16* h   = ws;            // [8192][1024] bf16
  u16* Qb  = ws +   T16;    // [64][2048][64]
  u16* Kb  = ws + 2*T16;    // [64][2048][64]
  u16* Vtb = ws + 3*T16;    // [64][64][2048]  (V transposed)
  u16* Wb  = ws + 4*T16;    // W_in bf16 [3072][1024]
  u16* Wob = Wb + (size_t)3*DMODEL*DMODEL; // W_o bf16 [1024][1024]
  u16* Ob  = h;             // reuse: h dead after gemm1
  float* out = (float*)d_out;

  const int na4 = 3*DMODEL*DMODEL/4;  // W_in float4 count
  const int nb4 = DMODEL*DMODEL/4;
  cast2_kernel<<<dim3((na4+nb4)/256), dim3(256), 0, stream>>>(W_in, Wb, W_o, Wob, na4);
  ln_kernel<<<dim3(MROWS), dim3(256), 0, stream>>>(x, h);
  gemm_bt<0><<<dim3(3*DMODEL/BN, MROWS/BM), dim3(256), 0, stream>>>(
      h, Wb, Qb, Kb, Vtb, nullptr, MROWS, 3*DMODEL, DMODEL);
  rope_kernel<<<dim3(SEQ*32/256), dim3(256), 0, stream>>>(Qb, Kb);
  attn_kernel<<<dim3(BHTOT, 64), dim3(128), 0, stream>>>(Qb, Kb, Vtb, Ob);
  gemm_bt<1><<<dim3(DMODEL/BN, MROWS/BM), dim3(256), 0, stream>>>(
      Ob, Wob, nullptr, nullptr, nullptr, out, MROWS, DMODEL, DMODEL);
}

// Round 5
// 340.326 us; speedup vs baseline: 1.0090x; 1.0090x over previous
//
#include <hip/hip_runtime.h>
#include <cstdint>

typedef unsigned short u16;
typedef short bf16x8 __attribute__((ext_vector_type(8)));
typedef float f32x4 __attribute__((ext_vector_type(4)));
typedef float f32x16 __attribute__((ext_vector_type(16)));
typedef unsigned int u32x2 __attribute__((ext_vector_type(2)));
typedef unsigned int u32x4 __attribute__((ext_vector_type(4)));

#define NB 4
#define SEQ 2048
#define DMODEL 1024
#define NHEADS 16
#define DHEAD 64
#define BHTOT (NB*NHEADS)   // 64
#define MROWS (NB*SEQ)      // 8192

__device__ __forceinline__ float bf2f(u16 u){
  union { unsigned int i; float f; } x; x.i = ((unsigned int)u)<<16; return x.f;
}
__device__ __forceinline__ u16 f2bf(float f){
  union { float f; unsigned int i; } x; x.f = f;
  unsigned int r = x.i + 0x7fffu + ((x.i>>16)&1u);
  return (u16)(r>>16);
}

typedef const __attribute__((address_space(1))) unsigned int* gas_t;
typedef __attribute__((address_space(3))) unsigned int* las_t;
__device__ __forceinline__ void async_cp16(const void* g, void* l){
  __builtin_amdgcn_global_load_lds((gas_t)g, (las_t)l, 16, 0, 0);
}

// permlane32_swap: rows 32-63 of a exchange with rows 0-31 of b
__device__ __forceinline__ void plswap(unsigned int &a, unsigned int &b){
#if __has_builtin(__builtin_amdgcn_permlane32_swap)
  u32x2 r = __builtin_amdgcn_permlane32_swap(a, b, false, false);
  a = r[0]; b = r[1];
#else
  asm("v_permlane32_swap_b32 %0, %1" : "+v"(a), "+v"(b));
#endif
}

// ---------------- fp32 -> bf16 cast for BOTH weights (one launch) ----------------
__global__ __launch_bounds__(256) void cast2_kernel(const float* __restrict__ wa, u16* __restrict__ oa,
    const float* __restrict__ wb, u16* __restrict__ ob, int na4){
  int i = blockIdx.x*256 + threadIdx.x;
  const float* src; u16* dst; int j;
  if(i < na4){ src = wa; dst = oa; j = i; }
  else       { src = wb; dst = ob; j = i - na4; }
  float4 v = ((const float4*)src)[j];
  ushort4 o;
  o.x=f2bf(v.x); o.y=f2bf(v.y); o.z=f2bf(v.z); o.w=f2bf(v.w);
  ((ushort4*)dst)[j] = o;
}

// ---------------- LayerNorm: x fp32 -> h bf16 (f32 stats) ----------------
__global__ __launch_bounds__(256) void ln_kernel(const float* __restrict__ x, u16* __restrict__ h){
  int row = blockIdx.x;
  const float* xr = x + (size_t)row*DMODEL;
  u16* hr = h + (size_t)row*DMODEL;
  int t = threadIdx.x;
  float4 v = ((const float4*)xr)[t];
  float f0=v.x, f1=v.y, f2=v.z, f3=v.w;
  float s = f0+f1+f2+f3;
  float q = f0*f0+f1*f1+f2*f2+f3*f3;
  #pragma unroll
  for(int off=32; off; off>>=1){ s += __shfl_xor(s, off); q += __shfl_xor(q, off); }
  __shared__ float ss[4], sq[4];
  int wv = t>>6, lane = t&63;
  if(lane==0){ ss[wv]=s; sq[wv]=q; }
  __syncthreads();
  s = ss[0]+ss[1]+ss[2]+ss[3];
  q = sq[0]+sq[1]+sq[2]+sq[3];
  float mu  = s * (1.0f/DMODEL);
  float var = q * (1.0f/DMODEL) - mu*mu;
  float rs  = rsqrtf(var + 1e-8f);
  ushort4 o;
  o.x=f2bf((f0-mu)*rs); o.y=f2bf((f1-mu)*rs); o.z=f2bf((f2-mu)*rs); o.w=f2bf((f3-mu)*rs);
  ((ushort4*)hr)[t] = o;
}

// ---------------- GEMM: C[m,n] = sum_k A[m,k]*Bm[n,k], bf16 MFMA ----------------
#define BM 128
#define BN 128
#define BK 32

template<int MODE>
__global__ __launch_bounds__(256) void gemm_bt(const u16* __restrict__ A, const u16* __restrict__ Bm,
    u16* __restrict__ Qb, u16* __restrict__ Kb, u16* __restrict__ Vtb, float* __restrict__ outf,
    int M, int N, int K){
  __shared__ u16 As[BM*BK];
  __shared__ u16 Bs[BN*BK];
  int t = threadIdx.x;
  int lane = t&63, wv = t>>6;
  int c = lane&15, g = lane>>4;
  int wm = wv>>1, wn = wv&1;
  int m0 = blockIdx.y*BM, n0 = blockIdx.x*BN;
  f32x4 acc[4][4] = {};
  for(int k0=0;k0<K;k0+=BK){
    __syncthreads();
    #pragma unroll
    for(int i=0;i<2;i++){
      int e = t*8 + i*2048;
      int r = e>>5, col = e&31;
      async_cp16(&A [(size_t)(m0+r)*K + k0 + col], &As[e]);
      async_cp16(&Bm[(size_t)(n0+r)*K + k0 + col], &Bs[e]);
    }
    __syncthreads();
    bf16x8 af[4], bfr[4];
    #pragma unroll
    for(int i=0;i<4;i++){
      af[i]  = *(const bf16x8*)(&As[(wm*64 + i*16 + c)*BK + g*8]);
      bfr[i] = *(const bf16x8*)(&Bs[(wn*64 + i*16 + c)*BK + g*8]);
    }
    #pragma unroll
    for(int mi=0;mi<4;mi++)
      #pragma unroll
      for(int ni=0;ni<4;ni++)
        acc[mi][ni] = __builtin_amdgcn_mfma_f32_16x16x32_bf16(af[mi], bfr[ni], acc[mi][ni], 0,0,0);
  }
  if(MODE==1){
    #pragma unroll
    for(int mi=0;mi<4;mi++){
      int mrow = m0 + wm*64 + mi*16 + g*4;
      #pragma unroll
      for(int ni=0;ni<4;ni++){
        int ncol = n0 + wn*64 + ni*16 + c;
        #pragma unroll
        for(int r=0;r<4;r++)
          outf[(size_t)(mrow+r)*N + ncol] = acc[mi][ni][r];
      }
    }
  } else {
    #pragma unroll
    for(int ni=0;ni<4;ni++){
      int n = n0 + wn*64 + ni*16 + c;
      int sel = n>>10, head = (n>>6)&15, d = n&63;
      #pragma unroll
      for(int mi=0;mi<4;mi++){
        int m = m0 + wm*64 + mi*16 + g*4;
        int b = m>>11, l = m&(SEQ-1);
        if(sel<2){
          u16* dst = (sel==0?Qb:Kb) + ((size_t)((b*NHEADS+head)*SEQ + l))*DHEAD + d;
          #pragma unroll
          for(int r=0;r<4;r++) dst[(size_t)r*DHEAD] = f2bf(acc[mi][ni][r]);
        } else {
          ushort4 pk;
          pk.x=f2bf(acc[mi][ni][0]); pk.y=f2bf(acc[mi][ni][1]);
          pk.z=f2bf(acc[mi][ni][2]); pk.w=f2bf(acc[mi][ni][3]);
          *(ushort4*)(&Vtb[((size_t)((b*NHEADS+head)*DHEAD + d))*SEQ + l]) = pk;
        }
      }
    }
  }
}

// ---------------- RoPE: one thread per (l,j), sincos once, loop over bh ----------------
// Q additionally pre-scaled by scale*log2(e) so attn's softmax is a bare exp2.
#define SC2 0.180336879f   // 0.125 * log2(e)
__global__ __launch_bounds__(256) void rope_kernel(u16* __restrict__ Q, u16* __restrict__ Kb){
  int tid = blockIdx.x*256 + threadIdx.x;   // SEQ*32 threads
  int j = tid&31, l = tid>>5;
  float inv = exp2f(-(float)j * (13.28771237954945f/32.0f)); // 10000^(-j/32)
  float sn, cs;
  sincosf((float)l*inv, &sn, &cs);
  size_t base = (size_t)l*DHEAD + 2*j;
  #pragma unroll 4
  for(int bh=0; bh<BHTOT; bh++){
    size_t off = base + (size_t)bh*SEQ*DHEAD;
    ushort2 q2 = *(ushort2*)(&Q[off]);
    float x1=bf2f(q2.x), x2=bf2f(q2.y);
    ushort2 o;
    o.x = f2bf((x1*cs - x2*sn)*SC2); o.y = f2bf((x1*sn + x2*cs)*SC2);
    *(ushort2*)(&Q[off]) = o;
    ushort2 k2 = *(ushort2*)(&Kb[off]);
    x1=bf2f(k2.x); x2=bf2f(k2.y);
    o.x = f2bf(x1*cs - x2*sn); o.y = f2bf(x1*sn + x2*cs);
    *(ushort2*)(&Kb[off]) = o;
  }
}

// ---------------- Flash attention: 32x32 swapped-QK^T, in-register P ----------------
// BISECT of round-4 failure: keep ONLY the structural change (wave w owns q-strip
// s = 2*sp + w, full k-range 0..s per wave, no cross-wave merge, no LDS, grid
// 2048 blocks = all-resident); revert the peel and raw-exp2 to the round-3-verified
// inner loop: guarded prefetch, runtime-masked EXPPACK(i==s), libm exp2f.
// Per tile: S^T = mfma32x32x16(K, Q) -> lane holds P[q=lane&31][k=(reg&3)+8*(reg>>2)+4*hl]
// P -> bf16 PV A-frags in registers: 8x v_cvt_pk_bf16_f32 + 4x permlane32_swap (T12).

#define LOADK32(TILE, KF) { int tb_=(TILE)*32; \
  _Pragma("unroll") for(int dk_=0;dk_<4;dk_++) \
    KF[dk_] = *(const bf16x8*)(&Kp[(size_t)(tb_ + c32)*DHEAD + dk_*16 + h8]); }

#define LOADV32(TILE, VF) { int tb_=(TILE)*32; \
  _Pragma("unroll") for(int dt_=0;dt_<2;dt_++) \
    _Pragma("unroll") for(int ks_=0;ks_<2;ks_++) \
      VF[dt_][ks_] = *(const bf16x8*)(&Vp[(size_t)(dt_*32 + c32)*SEQ + tb_ + ks_*16 + h8]); }

#define QKS32(KF) { \
  f32x16 z_ = {}; \
  z_ = __builtin_amdgcn_mfma_f32_32x32x16_bf16(KF[0], qf[0], z_, 0,0,0); \
  z_ = __builtin_amdgcn_mfma_f32_32x32x16_bf16(KF[1], qf[1], z_, 0,0,0); \
  z_ = __builtin_amdgcn_mfma_f32_32x32x16_bf16(KF[2], qf[2], z_, 0,0,0); \
  z_ = __builtin_amdgcn_mfma_f32_32x32x16_bf16(KF[3], qf[3], z_, 0,0,0); \
  sc = z_; }

// pk_[j] = packed bf16 of P for regs (2j, 2j+1); after the two swaps per half,
// pk words are exactly the PV A-frag words (k = 8*(lane>>5)+elem).
#define EXPPACK(MASKED) { \
  unsigned int pk_[8]; \
  _Pragma("unroll") for(int j_=0;j_<8;j_++){ \
    float a_ = exp2f(sc[2*j_]); \
    float b_ = exp2f(sc[2*j_+1]); \
    if(MASKED){ \
      int k0_ = ((2*j_)&3)   + 8*((2*j_)>>2)   + 4*hl; \
      int k1_ = ((2*j_+1)&3) + 8*((2*j_+1)>>2) + 4*hl; \
      a_ = (k0_ <= c32) ? a_ : 0.f; \
      b_ = (k1_ <= c32) ? b_ : 0.f; } \
    asm("v_cvt_pk_bf16_f32 %0, %1, %2" : "=v"(pk_[j_]) : "v"(a_), "v"(b_)); } \
  plswap(pk_[0], pk_[2]); \
  plswap(pk_[1], pk_[3]); \
  plswap(pk_[4], pk_[6]); \
  plswap(pk_[5], pk_[7]); \
  u32x4 wa_ = { pk_[0], pk_[1], pk_[2], pk_[3] }; \
  u32x4 wb_ = { pk_[4], pk_[5], pk_[6], pk_[7] }; \
  pa0 = __builtin_bit_cast(bf16x8, wa_); \
  pa1 = __builtin_bit_cast(bf16x8, wb_); }

#define PVM32(VF) { \
  lacc  = __builtin_amdgcn_mfma_f32_32x32x16_bf16(pa0, ones, lacc, 0,0,0); \
  lacc  = __builtin_amdgcn_mfma_f32_32x32x16_bf16(pa1, ones, lacc, 0,0,0); \
  oacc0 = __builtin_amdgcn_mfma_f32_32x32x16_bf16(pa0, VF[0][0], oacc0, 0,0,0); \
  oacc0 = __builtin_amdgcn_mfma_f32_32x32x16_bf16(pa1, VF[0][1], oacc0, 0,0,0); \
  oacc1 = __builtin_amdgcn_mfma_f32_32x32x16_bf16(pa0, VF[1][0], oacc1, 0,0,0); \
  oacc1 = __builtin_amdgcn_mfma_f32_32x32x16_bf16(pa1, VF[1][1], oacc1, 0,0,0); }

__global__ __launch_bounds__(128) void attn_kernel(const u16* __restrict__ Q, const u16* __restrict__ Kb,
    const u16* __restrict__ Vt, u16* __restrict__ O){
  int t = threadIdx.x, lane = t&63, w = t>>6;
  int c32 = lane&31, hl = lane>>5, h8 = hl*8;
  int bh = blockIdx.x;
  int b = bh>>4, hh = bh&15;
  int sp = 31 - blockIdx.y;      // long strip-pairs first
  int s = 2*sp + w;              // this wave's q strip
  int wrow = s*32;
  int nt = s+1;                  // tiles 0..s; tile s is the diag tile
  const u16* Qp = Q  + (size_t)bh*SEQ*DHEAD;
  const u16* Kp = Kb + (size_t)bh*SEQ*DHEAD;
  const u16* Vp = Vt + (size_t)bh*DHEAD*SEQ;
  bf16x8 ones;
  #pragma unroll
  for(int i=0;i<8;i++) ones[i] = (short)0x3f80;  // bf16 1.0

  // Q as B-frag: lane holds Q[wrow + (lane&31)][dk*16 + hl*8 .. +7]
  bf16x8 qf[4];
  #pragma unroll
  for(int dk=0;dk<4;dk++)
    qf[dk] = *(const bf16x8*)(&Qp[(size_t)(wrow + c32)*DHEAD + dk*16 + h8]);

  f32x16 oacc0 = {}, oacc1 = {}, lacc = {};
  f32x16 sc;
  bf16x8 kA[4], kB[4], vA[2][2], vB[2][2], pa0, pa1;

  LOADK32(0, kA); LOADV32(0, vA);
  int i = 0;
  #pragma unroll 1
  while(true){
    if(i+1 < nt){ LOADK32(i+1, kB); LOADV32(i+1, vB); }
    QKS32(kA);
    EXPPACK(i==s);
    PVM32(vA);
    i++;
    if(i >= nt) break;
    if(i+1 < nt){ LOADK32(i+1, kA); LOADV32(i+1, vA); }
    QKS32(kB);
    EXPPACK(i==s);
    PVM32(vB);
    i++;
    if(i >= nt) break;
  }

  // epilogue: each wave owns its full row sums -> direct normalized write
  // oacc row = (r&3)+8*(r>>2)+4*hl, col d = dt*32 + c32
  #pragma unroll
  for(int r=0;r<16;r++){
    int row = (r&3)+8*(r>>2)+4*hl;
    float linv = 1.0f/lacc[r];
    size_t o = ((size_t)(b*SEQ + wrow + row))*DMODEL + hh*DHEAD;
    O[o + c32]      = f2bf(oacc0[r]*linv);
    O[o + 32 + c32] = f2bf(oacc1[r]*linv);
  }
}

// ---------------- launch ----------------
extern "C" void kernel_launch(void* const* d_in, const int* in_sizes, int n_in,
                              void* d_out, int out_size, void* d_ws, size_t ws_size,
                              hipStream_t stream){
  const float* x    = (const float*)d_in[0];
  const float* W_in = (const float*)d_in[1];
  const float* W_o  = (const float*)d_in[2];
  u16* ws = (u16*)d_ws;
  const size_t T16 = (size_t)8*1024*1024;  // 8M bf16 elems = 16 MB per tensor
  u16* h   = ws;            // [8192][1024] bf16
  u16* Qb  = ws +   T16;    // [64][2048][64]
  u16* Kb  = ws + 2*T16;    // [64][2048][64]
  u16* Vtb = ws + 3*T16;    // [64][64][2048]  (V transposed)
  u16* Wb  = ws + 4*T16;    // W_in bf16 [3072][1024]
  u16* Wob = Wb + (size_t)3*DMODEL*DMODEL; // W_o bf16 [1024][1024]
  u16* Ob  = h;             // reuse: h dead after gemm1
  float* out = (float*)d_out;

  const int na4 = 3*DMODEL*DMODEL/4;  // W_in float4 count
  const int nb4 = DMODEL*DMODEL/4;
  cast2_kernel<<<dim3((na4+nb4)/256), dim3(256), 0, stream>>>(W_in, Wb, W_o, Wob, na4);
  ln_kernel<<<dim3(MROWS), dim3(256), 0, stream>>>(x, h);
  gemm_bt<0><<<dim3(3*DMODEL/BN, MROWS/BM), dim3(256), 0, stream>>>(
      h, Wb, Qb, Kb, Vtb, nullptr, MROWS, 3*DMODEL, DMODEL);
  rope_kernel<<<dim3(SEQ*32/256), dim3(256), 0, stream>>>(Qb, Kb);
  attn_kernel<<<dim3(BHTOT, 32), dim3(128), 0, stream>>>(Qb, Kb, Vtb, Ob);
  gemm_bt<1><<<dim3(DMODEL/BN, MROWS/BM), dim3(256), 0, stream>>>(
      Ob, Wob, nullptr, nullptr, nullptr, out, MROWS, DMODEL, DMODEL);
}

// Round 6
// 287.884 us; speedup vs baseline: 1.1928x; 1.1822x over previous
//
#include <hip/hip_runtime.h>
#include <cstdint>

typedef unsigned short u16;
typedef short bf16x8 __attribute__((ext_vector_type(8)));
typedef float f32x4 __attribute__((ext_vector_type(4)));
typedef float f32x16 __attribute__((ext_vector_type(16)));
typedef unsigned int u32x2 __attribute__((ext_vector_type(2)));
typedef unsigned int u32x4 __attribute__((ext_vector_type(4)));

#define NB 4
#define SEQ 2048
#define DMODEL 1024
#define NHEADS 16
#define DHEAD 64
#define BHTOT (NB*NHEADS)   // 64
#define MROWS (NB*SEQ)      // 8192

__device__ __forceinline__ float bf2f(u16 u){
  union { unsigned int i; float f; } x; x.i = ((unsigned int)u)<<16; return x.f;
}
__device__ __forceinline__ u16 f2bf(float f){
  union { float f; unsigned int i; } x; x.f = f;
  unsigned int r = x.i + 0x7fffu + ((x.i>>16)&1u);
  return (u16)(r>>16);
}

typedef const __attribute__((address_space(1))) unsigned int* gas_t;
typedef __attribute__((address_space(3))) unsigned int* las_t;
__device__ __forceinline__ void async_cp16(const void* g, void* l){
  __builtin_amdgcn_global_load_lds((gas_t)g, (las_t)l, 16, 0, 0);
}

// permlane32_swap: rows 32-63 of a exchange with rows 0-31 of b
__device__ __forceinline__ void plswap(unsigned int &a, unsigned int &b){
#if __has_builtin(__builtin_amdgcn_permlane32_swap)
  u32x2 r = __builtin_amdgcn_permlane32_swap(a, b, false, false);
  a = r[0]; b = r[1];
#else
  asm("v_permlane32_swap_b32 %0, %1" : "+v"(a), "+v"(b));
#endif
}

// ---------------- fp32 -> bf16 cast for BOTH weights (one launch) ----------------
__global__ __launch_bounds__(256) void cast2_kernel(const float* __restrict__ wa, u16* __restrict__ oa,
    const float* __restrict__ wb, u16* __restrict__ ob, int na4){
  int i = blockIdx.x*256 + threadIdx.x;
  const float* src; u16* dst; int j;
  if(i < na4){ src = wa; dst = oa; j = i; }
  else       { src = wb; dst = ob; j = i - na4; }
  float4 v = ((const float4*)src)[j];
  ushort4 o;
  o.x=f2bf(v.x); o.y=f2bf(v.y); o.z=f2bf(v.z); o.w=f2bf(v.w);
  ((ushort4*)dst)[j] = o;
}

// ---------------- LayerNorm: x fp32 -> h bf16 (f32 stats) ----------------
__global__ __launch_bounds__(256) void ln_kernel(const float* __restrict__ x, u16* __restrict__ h){
  int row = blockIdx.x;
  const float* xr = x + (size_t)row*DMODEL;
  u16* hr = h + (size_t)row*DMODEL;
  int t = threadIdx.x;
  float4 v = ((const float4*)xr)[t];
  float f0=v.x, f1=v.y, f2=v.z, f3=v.w;
  float s = f0+f1+f2+f3;
  float q = f0*f0+f1*f1+f2*f2+f3*f3;
  #pragma unroll
  for(int off=32; off; off>>=1){ s += __shfl_xor(s, off); q += __shfl_xor(q, off); }
  __shared__ float ss[4], sq[4];
  int wv = t>>6, lane = t&63;
  if(lane==0){ ss[wv]=s; sq[wv]=q; }
  __syncthreads();
  s = ss[0]+ss[1]+ss[2]+ss[3];
  q = sq[0]+sq[1]+sq[2]+sq[3];
  float mu  = s * (1.0f/DMODEL);
  float var = q * (1.0f/DMODEL) - mu*mu;
  float rs  = rsqrtf(var + 1e-8f);
  ushort4 o;
  o.x=f2bf((f0-mu)*rs); o.y=f2bf((f1-mu)*rs); o.z=f2bf((f2-mu)*rs); o.w=f2bf((f3-mu)*rs);
  ((ushort4*)hr)[t] = o;
}

// ---------------- GEMM: C[m,n] = sum_k A[m,k]*Bm[n,k], bf16 MFMA ----------------
#define BM 128
#define BN 128
#define BK 32

template<int MODE>
__global__ __launch_bounds__(256) void gemm_bt(const u16* __restrict__ A, const u16* __restrict__ Bm,
    u16* __restrict__ Qb, u16* __restrict__ Kb, u16* __restrict__ Vtb, float* __restrict__ outf,
    int M, int N, int K){
  __shared__ u16 As[BM*BK];
  __shared__ u16 Bs[BN*BK];
  int t = threadIdx.x;
  int lane = t&63, wv = t>>6;
  int c = lane&15, g = lane>>4;
  int wm = wv>>1, wn = wv&1;
  int m0 = blockIdx.y*BM, n0 = blockIdx.x*BN;
  f32x4 acc[4][4] = {};
  for(int k0=0;k0<K;k0+=BK){
    __syncthreads();
    #pragma unroll
    for(int i=0;i<2;i++){
      int e = t*8 + i*2048;
      int r = e>>5, col = e&31;
      async_cp16(&A [(size_t)(m0+r)*K + k0 + col], &As[e]);
      async_cp16(&Bm[(size_t)(n0+r)*K + k0 + col], &Bs[e]);
    }
    __syncthreads();
    bf16x8 af[4], bfr[4];
    #pragma unroll
    for(int i=0;i<4;i++){
      af[i]  = *(const bf16x8*)(&As[(wm*64 + i*16 + c)*BK + g*8]);
      bfr[i] = *(const bf16x8*)(&Bs[(wn*64 + i*16 + c)*BK + g*8]);
    }
    #pragma unroll
    for(int mi=0;mi<4;mi++)
      #pragma unroll
      for(int ni=0;ni<4;ni++)
        acc[mi][ni] = __builtin_amdgcn_mfma_f32_16x16x32_bf16(af[mi], bfr[ni], acc[mi][ni], 0,0,0);
  }
  if(MODE==1){
    #pragma unroll
    for(int mi=0;mi<4;mi++){
      int mrow = m0 + wm*64 + mi*16 + g*4;
      #pragma unroll
      for(int ni=0;ni<4;ni++){
        int ncol = n0 + wn*64 + ni*16 + c;
        #pragma unroll
        for(int r=0;r<4;r++)
          outf[(size_t)(mrow+r)*N + ncol] = acc[mi][ni][r];
      }
    }
  } else {
    #pragma unroll
    for(int ni=0;ni<4;ni++){
      int n = n0 + wn*64 + ni*16 + c;
      int sel = n>>10, head = (n>>6)&15, d = n&63;
      #pragma unroll
      for(int mi=0;mi<4;mi++){
        int m = m0 + wm*64 + mi*16 + g*4;
        int b = m>>11, l = m&(SEQ-1);
        if(sel<2){
          u16* dst = (sel==0?Qb:Kb) + ((size_t)((b*NHEADS+head)*SEQ + l))*DHEAD + d;
          #pragma unroll
          for(int r=0;r<4;r++) dst[(size_t)r*DHEAD] = f2bf(acc[mi][ni][r]);
        } else {
          ushort4 pk;
          pk.x=f2bf(acc[mi][ni][0]); pk.y=f2bf(acc[mi][ni][1]);
          pk.z=f2bf(acc[mi][ni][2]); pk.w=f2bf(acc[mi][ni][3]);
          *(ushort4*)(&Vtb[((size_t)((b*NHEADS+head)*DHEAD + d))*SEQ + l]) = pk;
        }
      }
    }
  }
}

// ---------------- RoPE: one thread per (l,j), sincos once, loop over bh ----------------
// Q additionally pre-scaled by scale*log2(e) so attn's softmax is a bare exp2.
#define SC2 0.180336879f   // 0.125 * log2(e)
__global__ __launch_bounds__(256) void rope_kernel(u16* __restrict__ Q, u16* __restrict__ Kb){
  int tid = blockIdx.x*256 + threadIdx.x;   // SEQ*32 threads
  int j = tid&31, l = tid>>5;
  float inv = exp2f(-(float)j * (13.28771237954945f/32.0f)); // 10000^(-j/32)
  float sn, cs;
  sincosf((float)l*inv, &sn, &cs);
  size_t base = (size_t)l*DHEAD + 2*j;
  #pragma unroll 4
  for(int bh=0; bh<BHTOT; bh++){
    size_t off = base + (size_t)bh*SEQ*DHEAD;
    ushort2 q2 = *(ushort2*)(&Q[off]);
    float x1=bf2f(q2.x), x2=bf2f(q2.y);
    ushort2 o;
    o.x = f2bf((x1*cs - x2*sn)*SC2); o.y = f2bf((x1*sn + x2*cs)*SC2);
    *(ushort2*)(&Q[off]) = o;
    ushort2 k2 = *(ushort2*)(&Kb[off]);
    x1=bf2f(k2.x); x2=bf2f(k2.y);
    o.x = f2bf(x1*cs - x2*sn); o.y = f2bf(x1*sn + x2*cs);
    *(ushort2*)(&Kb[off]) = o;
  }
}

// ---------------- Flash attention: 8-wave LDS-shared K/V, 32x32 swapped-QK^T ----------------
// Block = 512 threads (8 waves); wave w owns q-strip s = 8g + w. All waves share
// one double-buffered LDS K/V tile stream (tiles 0..8g+7): per-block traffic is
// 8 KB/tile instead of 8 KB/tile/WAVE -> total K/V cache traffic 1.06 GB -> 147 MB
// (the invariant ~7.5 TB/s L2-miss/L3 path was the 3x-replicated limiter).
// Staging: global_load_lds 16B, waves 0-3 stage K, waves 4-7 stage V, with
// PRE-SWIZZLED global source (rule 21: linear LDS dest + inverse-swizzled src +
// swizzled read). Swizzle: byte ^= ((byte>>7)&7)<<4 within each 8KB tile
// (16B chunk j ^= pair-row&7) -> both K[32][64] and Vt[64][32] reads conflict-free.
// Per tile: S^T = mfma32x32x16(K,Q); P->bf16 A-frags in registers (cvt_pk +
// permlane32_swap, T12); 8 MFMA/tile (4 QK + 4 PV). Row-sum accumulated in VALU
// on the live exp values (replaces the 2 lacc-MFMAs, saves 16 VGPR).

#define QKS32(KF) { \
  f32x16 z_ = {}; \
  z_ = __builtin_amdgcn_mfma_f32_32x32x16_bf16(KF[0], qf[0], z_, 0,0,0); \
  z_ = __builtin_amdgcn_mfma_f32_32x32x16_bf16(KF[1], qf[1], z_, 0,0,0); \
  z_ = __builtin_amdgcn_mfma_f32_32x32x16_bf16(KF[2], qf[2], z_, 0,0,0); \
  z_ = __builtin_amdgcn_mfma_f32_32x32x16_bf16(KF[3], qf[3], z_, 0,0,0); \
  sc = z_; }

// LDS reads with the tile swizzle (addresses stay 16B-aligned: only bits 4-6 flip)
#define LDK { \
  _Pragma("unroll") for(int dk_=0;dk_<4;dk_++){ \
    int kb_ = (c32*128 + dk_*32 + hl*16) ^ ((c32&7)<<4); \
    kf[dk_] = *(const bf16x8*)((const char*)(&Kls[cur][0]) + kb_); } }

#define LDV { \
  _Pragma("unroll") for(int dt_=0;dt_<2;dt_++) \
    _Pragma("unroll") for(int ks_=0;ks_<2;ks_++){ \
      int d_ = dt_*32 + c32; \
      int vb_ = (d_*64 + ks_*32 + hl*16) ^ (((d_>>1)&7)<<4); \
      vf[dt_][ks_] = *(const bf16x8*)((const char*)(&Vls[cur][0]) + vb_); } }

// pk_[j] = packed bf16 of P for regs (2j,2j+1); after the swaps, pk words are the
// PV A-frag words (k = 8*hl + elem). lrow accumulates this lane's half-row sum.
#define EXPPACK(MASKED) { \
  unsigned int pk_[8]; \
  _Pragma("unroll") for(int j_=0;j_<8;j_++){ \
    float a_ = exp2f(sc[2*j_]); \
    float b_ = exp2f(sc[2*j_+1]); \
    if(MASKED){ \
      int k0_ = ((2*j_)&3)   + 8*((2*j_)>>2)   + 4*hl; \
      int k1_ = ((2*j_+1)&3) + 8*((2*j_+1)>>2) + 4*hl; \
      a_ = (k0_ <= c32) ? a_ : 0.f; \
      b_ = (k1_ <= c32) ? b_ : 0.f; } \
    lrow += a_ + b_; \
    asm("v_cvt_pk_bf16_f32 %0, %1, %2" : "=v"(pk_[j_]) : "v"(a_), "v"(b_)); } \
  plswap(pk_[0], pk_[2]); \
  plswap(pk_[1], pk_[3]); \
  plswap(pk_[4], pk_[6]); \
  plswap(pk_[5], pk_[7]); \
  u32x4 wa_ = { pk_[0], pk_[1], pk_[2], pk_[3] }; \
  u32x4 wb_ = { pk_[4], pk_[5], pk_[6], pk_[7] }; \
  pa0 = __builtin_bit_cast(bf16x8, wa_); \
  pa1 = __builtin_bit_cast(bf16x8, wb_); }

#define PVM32 { \
  oacc0 = __builtin_amdgcn_mfma_f32_32x32x16_bf16(pa0, vf[0][0], oacc0, 0,0,0); \
  oacc0 = __builtin_amdgcn_mfma_f32_32x32x16_bf16(pa1, vf[0][1], oacc0, 0,0,0); \
  oacc1 = __builtin_amdgcn_mfma_f32_32x32x16_bf16(pa0, vf[1][0], oacc1, 0,0,0); \
  oacc1 = __builtin_amdgcn_mfma_f32_32x32x16_bf16(pa1, vf[1][1], oacc1, 0,0,0); }

__global__ __launch_bounds__(512, 4) void attn_kernel(const u16* __restrict__ Q, const u16* __restrict__ Kb,
    const u16* __restrict__ Vt, u16* __restrict__ O){
  __shared__ u16 Kls[2][2048];   // K tile [32 rows][64 d], swizzle-stored
  __shared__ u16 Vls[2][2048];   // Vt tile [64 d][32 l], swizzle-stored
  __shared__ float Ls[8][32];    // per-wave row sums
  int t = threadIdx.x, lane = t&63, w = t>>6;
  int c32 = lane&31, hl = lane>>5, h8 = hl*8;
  int bh = blockIdx.x;
  int b = bh>>4, hh = bh&15;
  int g = 7 - blockIdx.y;        // long groups first
  int s = g*8 + w;               // this wave's q strip (diag tile index)
  int wrow = s*32;
  int NT = g*8 + 8;              // block stages tiles 0..NT-1 (uniform in block)
  const u16* Qp = Q  + (size_t)bh*SEQ*DHEAD;
  const u16* Kp = Kb + (size_t)bh*SEQ*DHEAD;
  const u16* Vp = Vt + (size_t)bh*DHEAD*SEQ;

  // ---- staging role: waves 0-3 stage K (chunks 0..255), waves 4-7 stage V ----
  // Dest = linear 16B chunk c of the tile; source = inverse-swizzled global chunk:
  // pair-row p = c>>3, j_src = (c&7) ^ (p&7).
  bool isK = (w < 4);
  int cch = isK ? t : (t - 256);   // 0..255
  int prow = cch>>3;
  int jsrc = (cch&7) ^ (prow&7);
  size_t soff0, sstep;
  if(isK){
    // K chunk (row r=prow, 16B j): elems (r)*64 + j*8 ; +tb*64 per tile
    soff0 = (size_t)prow*64 + (size_t)jsrc*8;
    sstep = 32*64;
  } else {
    // V linear chunk c2 = p*8 + j maps to Vt elems (c2>>2)*SEQ + (c2&3)*8 ; +tb per tile
    int c2 = prow*8 + jsrc;
    soff0 = (size_t)(c2>>2)*SEQ + (size_t)(c2&3)*8;
    sstep = 32;
  }
  const u16* sbase = isK ? Kp : Vp;

  // Q as B-frag: lane holds Q[wrow + c32][dk*16 + h8 .. +7]
  bf16x8 qf[4];
  #pragma unroll
  for(int dk=0;dk<4;dk++)
    qf[dk] = *(const bf16x8*)(&Qp[(size_t)(wrow + c32)*DHEAD + dk*16 + h8]);

  f32x16 oacc0 = {}, oacc1 = {};
  float lrow = 0.f;
  f32x16 sc;
  bf16x8 kf[4], vf[2][2], pa0, pa1;

  // prologue: stage tile 0 into buf 0
  {
    u16* dst = isK ? &Kls[0][cch*8] : &Vls[0][cch*8];
    async_cp16(sbase + soff0, dst);
  }
  int cur = 0;
  #pragma unroll 1
  for(int tt=0; tt<NT; ++tt){
    __syncthreads();               // drains vmcnt (staging) + barrier
    if(tt+1 < NT){
      u16* dst = isK ? &Kls[cur^1][cch*8] : &Vls[cur^1][cch*8];
      async_cp16(sbase + soff0 + (size_t)(tt+1)*sstep, dst);
    }
    if(tt <= s){
      LDK; LDV;
      QKS32(kf);
      if(tt == s){ EXPPACK(1); } else { EXPPACK(0); }
      PVM32;
    }
    cur ^= 1;
  }

  // ---- epilogue: combine the two k-half sums, broadcast via tiny LDS, write O ----
  float lr = lrow + __shfl_xor(lrow, 32);   // rowsum for q = c32
  __syncthreads();
  if(hl==0) Ls[w][c32] = lr;
  __syncthreads();
  #pragma unroll
  for(int r=0;r<16;r++){
    int row = (r&3)+8*(r>>2)+4*hl;
    float linv = 1.0f/Ls[w][row];
    size_t o = ((size_t)(b*SEQ + wrow + row))*DMODEL + hh*DHEAD;
    O[o + c32]      = f2bf(oacc0[r]*linv);
    O[o + 32 + c32] = f2bf(oacc1[r]*linv);
  }
}

// ---------------- launch ----------------
extern "C" void kernel_launch(void* const* d_in, const int* in_sizes, int n_in,
                              void* d_out, int out_size, void* d_ws, size_t ws_size,
                              hipStream_t stream){
  const float* x    = (const float*)d_in[0];
  const float* W_in = (const float*)d_in[1];
  const float* W_o  = (const float*)d_in[2];
  u16* ws = (u16*)d_ws;
  const size_t T16 = (size_t)8*1024*1024;  // 8M bf16 elems = 16 MB per tensor
  u16* h   = ws;            // [8192][1024] bf16
  u16* Qb  = ws +   T16;    // [64][2048][64]
  u16* Kb  = ws + 2*T16;    // [64][2048][64]
  u16* Vtb = ws + 3*T16;    // [64][64][2048]  (V transposed)
  u16* Wb  = ws + 4*T16;    // W_in bf16 [3072][1024]
  u16* Wob = Wb + (size_t)3*DMODEL*DMODEL; // W_o bf16 [1024][1024]
  u16* Ob  = h;             // reuse: h dead after gemm1
  float* out = (float*)d_out;

  const int na4 = 3*DMODEL*DMODEL/4;  // W_in float4 count
  const int nb4 = DMODEL*DMODEL/4;
  cast2_kernel<<<dim3((na4+nb4)/256), dim3(256), 0, stream>>>(W_in, Wb, W_o, Wob, na4);
  ln_kernel<<<dim3(MROWS), dim3(256), 0, stream>>>(x, h);
  gemm_bt<0><<<dim3(3*DMODEL/BN, MROWS/BM), dim3(256), 0, stream>>>(
      h, Wb, Qb, Kb, Vtb, nullptr, MROWS, 3*DMODEL, DMODEL);
  rope_kernel<<<dim3(SEQ*32/256), dim3(256), 0, stream>>>(Qb, Kb);
  attn_kernel<<<dim3(BHTOT, 8), dim3(512), 0, stream>>>(Qb, Kb, Vtb, Ob);
  gemm_bt<1><<<dim3(DMODEL/BN, MROWS/BM), dim3(256), 0, stream>>>(
      Ob, Wob, nullptr, nullptr, nullptr, out, MROWS, DMODEL, DMODEL);
}

// Round 7
// 274.258 us; speedup vs baseline: 1.2520x; 1.0497x over previous
//
#include <hip/hip_runtime.h>
#include <cstdint>

typedef unsigned short u16;
typedef short bf16x8 __attribute__((ext_vector_type(8)));
typedef float f32x4 __attribute__((ext_vector_type(4)));
typedef float f32x16 __attribute__((ext_vector_type(16)));
typedef unsigned int u32x2 __attribute__((ext_vector_type(2)));
typedef unsigned int u32x4 __attribute__((ext_vector_type(4)));

#define NB 4
#define SEQ 2048
#define DMODEL 1024
#define NHEADS 16
#define DHEAD 64
#define BHTOT (NB*NHEADS)   // 64
#define MROWS (NB*SEQ)      // 8192

__device__ __forceinline__ float bf2f(u16 u){
  union { unsigned int i; float f; } x; x.i = ((unsigned int)u)<<16; return x.f;
}
__device__ __forceinline__ u16 f2bf(float f){
  union { float f; unsigned int i; } x; x.f = f;
  unsigned int r = x.i + 0x7fffu + ((x.i>>16)&1u);
  return (u16)(r>>16);
}

typedef const __attribute__((address_space(1))) unsigned int* gas_t;
typedef __attribute__((address_space(3))) unsigned int* las_t;
__device__ __forceinline__ void async_cp16(const void* g, void* l){
  __builtin_amdgcn_global_load_lds((gas_t)g, (las_t)l, 16, 0, 0);
}

// permlane32_swap: rows 32-63 of a exchange with rows 0-31 of b
__device__ __forceinline__ void plswap(unsigned int &a, unsigned int &b){
#if __has_builtin(__builtin_amdgcn_permlane32_swap)
  u32x2 r = __builtin_amdgcn_permlane32_swap(a, b, false, false);
  a = r[0]; b = r[1];
#else
  asm("v_permlane32_swap_b32 %0, %1" : "+v"(a), "+v"(b));
#endif
}

// ---------------- fp32 -> bf16 cast for BOTH weights (one launch) ----------------
__global__ __launch_bounds__(256) void cast2_kernel(const float* __restrict__ wa, u16* __restrict__ oa,
    const float* __restrict__ wb, u16* __restrict__ ob, int na4){
  int i = blockIdx.x*256 + threadIdx.x;
  const float* src; u16* dst; int j;
  if(i < na4){ src = wa; dst = oa; j = i; }
  else       { src = wb; dst = ob; j = i - na4; }
  float4 v = ((const float4*)src)[j];
  ushort4 o;
  o.x=f2bf(v.x); o.y=f2bf(v.y); o.z=f2bf(v.z); o.w=f2bf(v.w);
  ((ushort4*)dst)[j] = o;
}

// ---------------- LayerNorm: x fp32 -> h bf16 (f32 stats) ----------------
__global__ __launch_bounds__(256) void ln_kernel(const float* __restrict__ x, u16* __restrict__ h){
  int row = blockIdx.x;
  const float* xr = x + (size_t)row*DMODEL;
  u16* hr = h + (size_t)row*DMODEL;
  int t = threadIdx.x;
  float4 v = ((const float4*)xr)[t];
  float f0=v.x, f1=v.y, f2=v.z, f3=v.w;
  float s = f0+f1+f2+f3;
  float q = f0*f0+f1*f1+f2*f2+f3*f3;
  #pragma unroll
  for(int off=32; off; off>>=1){ s += __shfl_xor(s, off); q += __shfl_xor(q, off); }
  __shared__ float ss[4], sq[4];
  int wv = t>>6, lane = t&63;
  if(lane==0){ ss[wv]=s; sq[wv]=q; }
  __syncthreads();
  s = ss[0]+ss[1]+ss[2]+ss[3];
  q = sq[0]+sq[1]+sq[2]+sq[3];
  float mu  = s * (1.0f/DMODEL);
  float var = q * (1.0f/DMODEL) - mu*mu;
  float rs  = rsqrtf(var + 1e-8f);
  ushort4 o;
  o.x=f2bf((f0-mu)*rs); o.y=f2bf((f1-mu)*rs); o.z=f2bf((f2-mu)*rs); o.w=f2bf((f3-mu)*rs);
  ((ushort4*)hr)[t] = o;
}

// ---------------- GEMM: C[m,n] = sum_k A[m,k]*Bm[n,k], bf16 MFMA ----------------
// Double-buffered LDS (one barrier per K-step, prefetch issued before compute so
// the ds_read+MFMA of tile k hides the global latency of tile k+1 — the attn-r6
// proven loop), plus pair-row XOR swizzle (rule 21: linear LDS dest, inverse-
// swizzled global source, swizzled read): 16B chunk j ^= (pairrow&7) within each
// 128B pair of rows -> 16-lane ds_read_b128 groups hit all 8 bank-sets, 2 lanes
// each (free), instead of 2 sets x 8 lanes (8-way conflict).
#define BM 128
#define BN 128
#define BK 32

template<int MODE>
__global__ __launch_bounds__(256) void gemm_bt(const u16* __restrict__ A, const u16* __restrict__ Bm,
    u16* __restrict__ Qb, u16* __restrict__ Kb, u16* __restrict__ Vtb, float* __restrict__ outf,
    int M, int N, int K){
  __shared__ u16 As[2][BM*BK];
  __shared__ u16 Bs[2][BN*BK];
  int t = threadIdx.x;
  int lane = t&63, wv = t>>6;
  int c = lane&15, g = lane>>4;
  int wm = wv>>1, wn = wv&1;
  int m0 = blockIdx.y*BM, n0 = blockIdx.x*BN;

  // staging source offsets (within-tile), inverse-swizzled:
  // chunk cc: pair-row p = cc>>3, slot j = cc&7, jsrc = j ^ (p&7);
  // global row = p*2 + (jsrc>>2), col = (jsrc&3)*8
  int p0 = t>>3,        j0 = t&7;        int js0 = j0 ^ (p0&7);
  int p1 = (t+256)>>3,  j1 = t&7;        int js1 = j1 ^ (p1&7);
  size_t aoff0 = (size_t)(p0*2 + (js0>>2))*K + (js0&3)*8;
  size_t aoff1 = (size_t)(p1*2 + (js1>>2))*K + (js1&3)*8;
  const u16* Abase = A  + (size_t)m0*K;
  const u16* Bbase = Bm + (size_t)n0*K;

  f32x4 acc[4][4] = {};

  // prologue: stage tile 0 into buf 0
  async_cp16(Abase + aoff0, &As[0][t*8]);
  async_cp16(Abase + aoff1, &As[0][(t+256)*8]);
  async_cp16(Bbase + aoff0, &Bs[0][t*8]);
  async_cp16(Bbase + aoff1, &Bs[0][(t+256)*8]);

  int cur = 0;
  for(int k0=0;k0<K;k0+=BK){
    __syncthreads();   // drains staging of buf[cur]; orders prev-iter reads of buf[cur^1]
    if(k0+BK < K){
      int nb = cur^1;
      async_cp16(Abase + (k0+BK) + aoff0, &As[nb][t*8]);
      async_cp16(Abase + (k0+BK) + aoff1, &As[nb][(t+256)*8]);
      async_cp16(Bbase + (k0+BK) + aoff0, &Bs[nb][t*8]);
      async_cp16(Bbase + (k0+BK) + aoff1, &Bs[nb][(t+256)*8]);
    }
    bf16x8 af[4], bfr[4];
    #pragma unroll
    for(int i=0;i<4;i++){
      int ra = wm*64 + i*16 + c;
      int qa = ((ra&1)*4 + g) ^ ((ra>>1)&7);
      af[i]  = *(const bf16x8*)(&As[cur][(ra>>1)*64 + qa*8]);
      int rb = wn*64 + i*16 + c;
      int qb = ((rb&1)*4 + g) ^ ((rb>>1)&7);
      bfr[i] = *(const bf16x8*)(&Bs[cur][(rb>>1)*64 + qb*8]);
    }
    #pragma unroll
    for(int mi=0;mi<4;mi++)
      #pragma unroll
      for(int ni=0;ni<4;ni++)
        acc[mi][ni] = __builtin_amdgcn_mfma_f32_16x16x32_bf16(af[mi], bfr[ni], acc[mi][ni], 0,0,0);
    cur ^= 1;
  }
  if(MODE==1){
    #pragma unroll
    for(int mi=0;mi<4;mi++){
      int mrow = m0 + wm*64 + mi*16 + g*4;
      #pragma unroll
      for(int ni=0;ni<4;ni++){
        int ncol = n0 + wn*64 + ni*16 + c;
        #pragma unroll
        for(int r=0;r<4;r++)
          outf[(size_t)(mrow+r)*N + ncol] = acc[mi][ni][r];
      }
    }
  } else {
    #pragma unroll
    for(int ni=0;ni<4;ni++){
      int n = n0 + wn*64 + ni*16 + c;
      int sel = n>>10, head = (n>>6)&15, d = n&63;
      #pragma unroll
      for(int mi=0;mi<4;mi++){
        int m = m0 + wm*64 + mi*16 + g*4;
        int b = m>>11, l = m&(SEQ-1);
        if(sel<2){
          u16* dst = (sel==0?Qb:Kb) + ((size_t)((b*NHEADS+head)*SEQ + l))*DHEAD + d;
          #pragma unroll
          for(int r=0;r<4;r++) dst[(size_t)r*DHEAD] = f2bf(acc[mi][ni][r]);
        } else {
          ushort4 pk;
          pk.x=f2bf(acc[mi][ni][0]); pk.y=f2bf(acc[mi][ni][1]);
          pk.z=f2bf(acc[mi][ni][2]); pk.w=f2bf(acc[mi][ni][3]);
          *(ushort4*)(&Vtb[((size_t)((b*NHEADS+head)*DHEAD + d))*SEQ + l]) = pk;
        }
      }
    }
  }
}

// ---------------- RoPE: one thread per (l,j), sincos once, loop over bh ----------------
// Q additionally pre-scaled by scale*log2(e) so attn's softmax is a bare exp2.
#define SC2 0.180336879f   // 0.125 * log2(e)
__global__ __launch_bounds__(256) void rope_kernel(u16* __restrict__ Q, u16* __restrict__ Kb){
  int tid = blockIdx.x*256 + threadIdx.x;   // SEQ*32 threads
  int j = tid&31, l = tid>>5;
  float inv = exp2f(-(float)j * (13.28771237954945f/32.0f)); // 10000^(-j/32)
  float sn, cs;
  sincosf((float)l*inv, &sn, &cs);
  size_t base = (size_t)l*DHEAD + 2*j;
  #pragma unroll 4
  for(int bh=0; bh<BHTOT; bh++){
    size_t off = base + (size_t)bh*SEQ*DHEAD;
    ushort2 q2 = *(ushort2*)(&Q[off]);
    float x1=bf2f(q2.x), x2=bf2f(q2.y);
    ushort2 o;
    o.x = f2bf((x1*cs - x2*sn)*SC2); o.y = f2bf((x1*sn + x2*cs)*SC2);
    *(ushort2*)(&Q[off]) = o;
    ushort2 k2 = *(ushort2*)(&Kb[off]);
    x1=bf2f(k2.x); x2=bf2f(k2.y);
    o.x = f2bf(x1*cs - x2*sn); o.y = f2bf(x1*sn + x2*cs);
    *(ushort2*)(&Kb[off]) = o;
  }
}

// ---------------- Flash attention: 8-wave LDS-shared K/V, 32x32 swapped-QK^T ----------------
// Block = 512 threads (8 waves); wave w owns q-strip s = 8g + w. All waves share
// one double-buffered LDS K/V tile stream (tiles 0..8g+7): per-block traffic is
// 8 KB/tile instead of 8 KB/tile/WAVE.
// Staging: global_load_lds 16B, waves 0-3 stage K, waves 4-7 stage V, with
// PRE-SWIZZLED global source (rule 21). Swizzle: 16B chunk j ^= pair-row&7 ->
// both K[32][64] and Vt[64][32] reads conflict-free.
// Per tile: S^T = mfma32x32x16(K,Q); P->bf16 A-frags in registers (cvt_pk +
// permlane32_swap, T12); 8 MFMA/tile (4 QK + 4 PV). Row-sum accumulated in VALU.

#define QKS32(KF) { \
  f32x16 z_ = {}; \
  z_ = __builtin_amdgcn_mfma_f32_32x32x16_bf16(KF[0], qf[0], z_, 0,0,0); \
  z_ = __builtin_amdgcn_mfma_f32_32x32x16_bf16(KF[1], qf[1], z_, 0,0,0); \
  z_ = __builtin_amdgcn_mfma_f32_32x32x16_bf16(KF[2], qf[2], z_, 0,0,0); \
  z_ = __builtin_amdgcn_mfma_f32_32x32x16_bf16(KF[3], qf[3], z_, 0,0,0); \
  sc = z_; }

// LDS reads with the tile swizzle (addresses stay 16B-aligned: only bits 4-6 flip)
#define LDK { \
  _Pragma("unroll") for(int dk_=0;dk_<4;dk_++){ \
    int kb_ = (c32*128 + dk_*32 + hl*16) ^ ((c32&7)<<4); \
    kf[dk_] = *(const bf16x8*)((const char*)(&Kls[cur][0]) + kb_); } }

#define LDV { \
  _Pragma("unroll") for(int dt_=0;dt_<2;dt_++) \
    _Pragma("unroll") for(int ks_=0;ks_<2;ks_++){ \
      int d_ = dt_*32 + c32; \
      int vb_ = (d_*64 + ks_*32 + hl*16) ^ (((d_>>1)&7)<<4); \
      vf[dt_][ks_] = *(const bf16x8*)((const char*)(&Vls[cur][0]) + vb_); } }

// pk_[j] = packed bf16 of P for regs (2j,2j+1); after the swaps, pk words are the
// PV A-frag words (k = 8*hl + elem). lrow accumulates this lane's half-row sum.
#define EXPPACK(MASKED) { \
  unsigned int pk_[8]; \
  _Pragma("unroll") for(int j_=0;j_<8;j_++){ \
    float a_ = exp2f(sc[2*j_]); \
    float b_ = exp2f(sc[2*j_+1]); \
    if(MASKED){ \
      int k0_ = ((2*j_)&3)   + 8*((2*j_)>>2)   + 4*hl; \
      int k1_ = ((2*j_+1)&3) + 8*((2*j_+1)>>2) + 4*hl; \
      a_ = (k0_ <= c32) ? a_ : 0.f; \
      b_ = (k1_ <= c32) ? b_ : 0.f; } \
    lrow += a_ + b_; \
    asm("v_cvt_pk_bf16_f32 %0, %1, %2" : "=v"(pk_[j_]) : "v"(a_), "v"(b_)); } \
  plswap(pk_[0], pk_[2]); \
  plswap(pk_[1], pk_[3]); \
  plswap(pk_[4], pk_[6]); \
  plswap(pk_[5], pk_[7]); \
  u32x4 wa_ = { pk_[0], pk_[1], pk_[2], pk_[3] }; \
  u32x4 wb_ = { pk_[4], pk_[5], pk_[6], pk_[7] }; \
  pa0 = __builtin_bit_cast(bf16x8, wa_); \
  pa1 = __builtin_bit_cast(bf16x8, wb_); }

#define PVM32 { \
  oacc0 = __builtin_amdgcn_mfma_f32_32x32x16_bf16(pa0, vf[0][0], oacc0, 0,0,0); \
  oacc0 = __builtin_amdgcn_mfma_f32_32x32x16_bf16(pa1, vf[0][1], oacc0, 0,0,0); \
  oacc1 = __builtin_amdgcn_mfma_f32_32x32x16_bf16(pa0, vf[1][0], oacc1, 0,0,0); \
  oacc1 = __builtin_amdgcn_mfma_f32_32x32x16_bf16(pa1, vf[1][1], oacc1, 0,0,0); }

__global__ __launch_bounds__(512, 4) void attn_kernel(const u16* __restrict__ Q, const u16* __restrict__ Kb,
    const u16* __restrict__ Vt, u16* __restrict__ O){
  __shared__ u16 Kls[2][2048];   // K tile [32 rows][64 d], swizzle-stored
  __shared__ u16 Vls[2][2048];   // Vt tile [64 d][32 l], swizzle-stored
  __shared__ float Ls[8][32];    // per-wave row sums
  int t = threadIdx.x, lane = t&63, w = t>>6;
  int c32 = lane&31, hl = lane>>5, h8 = hl*8;
  int bh = blockIdx.x;
  int b = bh>>4, hh = bh&15;
  int g = 7 - blockIdx.y;        // long groups first
  int s = g*8 + w;               // this wave's q strip (diag tile index)
  int wrow = s*32;
  int NT = g*8 + 8;              // block stages tiles 0..NT-1 (uniform in block)
  const u16* Qp = Q  + (size_t)bh*SEQ*DHEAD;
  const u16* Kp = Kb + (size_t)bh*SEQ*DHEAD;
  const u16* Vp = Vt + (size_t)bh*DHEAD*SEQ;

  // ---- staging role: waves 0-3 stage K (chunks 0..255), waves 4-7 stage V ----
  bool isK = (w < 4);
  int cch = isK ? t : (t - 256);   // 0..255
  int prow = cch>>3;
  int jsrc = (cch&7) ^ (prow&7);
  size_t soff0, sstep;
  if(isK){
    soff0 = (size_t)prow*64 + (size_t)jsrc*8;
    sstep = 32*64;
  } else {
    int c2 = prow*8 + jsrc;
    soff0 = (size_t)(c2>>2)*SEQ + (size_t)(c2&3)*8;
    sstep = 32;
  }
  const u16* sbase = isK ? Kp : Vp;

  // Q as B-frag: lane holds Q[wrow + c32][dk*16 + h8 .. +7]
  bf16x8 qf[4];
  #pragma unroll
  for(int dk=0;dk<4;dk++)
    qf[dk] = *(const bf16x8*)(&Qp[(size_t)(wrow + c32)*DHEAD + dk*16 + h8]);

  f32x16 oacc0 = {}, oacc1 = {};
  float lrow = 0.f;
  f32x16 sc;
  bf16x8 kf[4], vf[2][2], pa0, pa1;

  // prologue: stage tile 0 into buf 0
  {
    u16* dst = isK ? &Kls[0][cch*8] : &Vls[0][cch*8];
    async_cp16(sbase + soff0, dst);
  }
  int cur = 0;
  #pragma unroll 1
  for(int tt=0; tt<NT; ++tt){
    __syncthreads();               // drains vmcnt (staging) + barrier
    if(tt+1 < NT){
      u16* dst = isK ? &Kls[cur^1][cch*8] : &Vls[cur^1][cch*8];
      async_cp16(sbase + soff0 + (size_t)(tt+1)*sstep, dst);
    }
    if(tt <= s){
      LDK; LDV;
      QKS32(kf);
      if(tt == s){ EXPPACK(1); } else { EXPPACK(0); }
      PVM32;
    }
    cur ^= 1;
  }

  // ---- epilogue: combine the two k-half sums, broadcast via tiny LDS, write O ----
  float lr = lrow + __shfl_xor(lrow, 32);   // rowsum for q = c32
  __syncthreads();
  if(hl==0) Ls[w][c32] = lr;
  __syncthreads();
  #pragma unroll
  for(int r=0;r<16;r++){
    int row = (r&3)+8*(r>>2)+4*hl;
    float linv = 1.0f/Ls[w][row];
    size_t o = ((size_t)(b*SEQ + wrow + row))*DMODEL + hh*DHEAD;
    O[o + c32]      = f2bf(oacc0[r]*linv);
    O[o + 32 + c32] = f2bf(oacc1[r]*linv);
  }
}

// ---------------- launch ----------------
extern "C" void kernel_launch(void* const* d_in, const int* in_sizes, int n_in,
                              void* d_out, int out_size, void* d_ws, size_t ws_size,
                              hipStream_t stream){
  const float* x    = (const float*)d_in[0];
  const float* W_in = (const float*)d_in[1];
  const float* W_o  = (const float*)d_in[2];
  u16* ws = (u16*)d_ws;
  const size_t T16 = (size_t)8*1024*1024;  // 8M bf16 elems = 16 MB per tensor
  u16* h   = ws;            // [8192][1024] bf16
  u16* Qb  = ws +   T16;    // [64][2048][64]
  u16* Kb  = ws + 2*T16;    // [64][2048][64]
  u16* Vtb = ws + 3*T16;    // [64][64][2048]  (V transposed)
  u16* Wb  = ws + 4*T16;    // W_in bf16 [3072][1024]
  u16* Wob = Wb + (size_t)3*DMODEL*DMODEL; // W_o bf16 [1024][1024]
  u16* Ob  = h;             // reuse: h dead after gemm1
  float* out = (float*)d_out;

  const int na4 = 3*DMODEL*DMODEL/4;  // W_in float4 count
  const int nb4 = DMODEL*DMODEL/4;
  cast2_kernel<<<dim3((na4+nb4)/256), dim3(256), 0, stream>>>(W_in, Wb, W_o, Wob, na4);
  ln_kernel<<<dim3(MROWS), dim3(256), 0, stream>>>(x, h);
  gemm_bt<0><<<dim3(3*DMODEL/BN, MROWS/BM), dim3(256), 0, stream>>>(
      h, Wb, Qb, Kb, Vtb, nullptr, MROWS, 3*DMODEL, DMODEL);
  rope_kernel<<<dim3(SEQ*32/256), dim3(256), 0, stream>>>(Qb, Kb);
  attn_kernel<<<dim3(BHTOT, 8), dim3(512), 0, stream>>>(Qb, Kb, Vtb, Ob);
  gemm_bt<1><<<dim3(DMODEL/BN, MROWS/BM), dim3(256), 0, stream>>>(
      Ob, Wob, nullptr, nullptr, nullptr, out, MROWS, DMODEL, DMODEL);
}

// Round 8
// 272.489 us; speedup vs baseline: 1.2601x; 1.0065x over previous
//
#include <hip/hip_runtime.h>
#include <cstdint>

typedef unsigned short u16;
typedef short bf16x8 __attribute__((ext_vector_type(8)));
typedef float f32x4 __attribute__((ext_vector_type(4)));
typedef float f32x16 __attribute__((ext_vector_type(16)));
typedef unsigned int u32x2 __attribute__((ext_vector_type(2)));
typedef unsigned int u32x4 __attribute__((ext_vector_type(4)));

#define NB 4
#define SEQ 2048
#define DMODEL 1024
#define NHEADS 16
#define DHEAD 64
#define BHTOT (NB*NHEADS)   // 64
#define MROWS (NB*SEQ)      // 8192

__device__ __forceinline__ float bf2f(u16 u){
  union { unsigned int i; float f; } x; x.i = ((unsigned int)u)<<16; return x.f;
}
__device__ __forceinline__ u16 f2bf(float f){
  union { float f; unsigned int i; } x; x.f = f;
  unsigned int r = x.i + 0x7fffu + ((x.i>>16)&1u);
  return (u16)(r>>16);
}

typedef const __attribute__((address_space(1))) unsigned int* gas_t;
typedef __attribute__((address_space(3))) unsigned int* las_t;
__device__ __forceinline__ void async_cp16(const void* g, void* l){
  __builtin_amdgcn_global_load_lds((gas_t)g, (las_t)l, 16, 0, 0);
}

// permlane32_swap: rows 32-63 of a exchange with rows 0-31 of b
__device__ __forceinline__ void plswap(unsigned int &a, unsigned int &b){
#if __has_builtin(__builtin_amdgcn_permlane32_swap)
  u32x2 r = __builtin_amdgcn_permlane32_swap(a, b, false, false);
  a = r[0]; b = r[1];
#else
  asm("v_permlane32_swap_b32 %0, %1" : "+v"(a), "+v"(b));
#endif
}

// ---------------- fp32 -> bf16 cast for BOTH weights (one launch) ----------------
__global__ __launch_bounds__(256) void cast2_kernel(const float* __restrict__ wa, u16* __restrict__ oa,
    const float* __restrict__ wb, u16* __restrict__ ob, int na4){
  int i = blockIdx.x*256 + threadIdx.x;
  const float* src; u16* dst; int j;
  if(i < na4){ src = wa; dst = oa; j = i; }
  else       { src = wb; dst = ob; j = i - na4; }
  float4 v = ((const float4*)src)[j];
  ushort4 o;
  o.x=f2bf(v.x); o.y=f2bf(v.y); o.z=f2bf(v.z); o.w=f2bf(v.w);
  ((ushort4*)dst)[j] = o;
}

// ---------------- LayerNorm: x fp32 -> h bf16 (f32 stats) ----------------
__global__ __launch_bounds__(256) void ln_kernel(const float* __restrict__ x, u16* __restrict__ h){
  int row = blockIdx.x;
  const float* xr = x + (size_t)row*DMODEL;
  u16* hr = h + (size_t)row*DMODEL;
  int t = threadIdx.x;
  float4 v = ((const float4*)xr)[t];
  float f0=v.x, f1=v.y, f2=v.z, f3=v.w;
  float s = f0+f1+f2+f3;
  float q = f0*f0+f1*f1+f2*f2+f3*f3;
  #pragma unroll
  for(int off=32; off; off>>=1){ s += __shfl_xor(s, off); q += __shfl_xor(q, off); }
  __shared__ float ss[4], sq[4];
  int wv = t>>6, lane = t&63;
  if(lane==0){ ss[wv]=s; sq[wv]=q; }
  __syncthreads();
  s = ss[0]+ss[1]+ss[2]+ss[3];
  q = sq[0]+sq[1]+sq[2]+sq[3];
  float mu  = s * (1.0f/DMODEL);
  float var = q * (1.0f/DMODEL) - mu*mu;
  float rs  = rsqrtf(var + 1e-8f);
  ushort4 o;
  o.x=f2bf((f0-mu)*rs); o.y=f2bf((f1-mu)*rs); o.z=f2bf((f2-mu)*rs); o.w=f2bf((f3-mu)*rs);
  ((ushort4*)hr)[t] = o;
}

// ---------------- GEMM: C[m,n] = sum_k A[m,k]*Bm[n,k], bf16 MFMA ----------------
// Double-buffered LDS (one barrier per K-step, prefetch before compute) + pair-row
// XOR swizzle (rule 21: linear LDS dest, inverse-swizzled global source, swizzled
// read): 16B chunk j ^= (pairrow&7) -> conflict-free ds_read_b128.
#define BM 128
#define BN 128
#define BK 32

template<int MODE>
__global__ __launch_bounds__(256) void gemm_bt(const u16* __restrict__ A, const u16* __restrict__ Bm,
    u16* __restrict__ Qb, u16* __restrict__ Kb, u16* __restrict__ Vtb, float* __restrict__ outf,
    int M, int N, int K){
  __shared__ u16 As[2][BM*BK];
  __shared__ u16 Bs[2][BN*BK];
  int t = threadIdx.x;
  int lane = t&63, wv = t>>6;
  int c = lane&15, g = lane>>4;
  int wm = wv>>1, wn = wv&1;
  int m0 = blockIdx.y*BM, n0 = blockIdx.x*BN;

  int p0 = t>>3,        j0 = t&7;        int js0 = j0 ^ (p0&7);
  int p1 = (t+256)>>3,  j1 = t&7;        int js1 = j1 ^ (p1&7);
  size_t aoff0 = (size_t)(p0*2 + (js0>>2))*K + (js0&3)*8;
  size_t aoff1 = (size_t)(p1*2 + (js1>>2))*K + (js1&3)*8;
  const u16* Abase = A  + (size_t)m0*K;
  const u16* Bbase = Bm + (size_t)n0*K;

  f32x4 acc[4][4] = {};

  async_cp16(Abase + aoff0, &As[0][t*8]);
  async_cp16(Abase + aoff1, &As[0][(t+256)*8]);
  async_cp16(Bbase + aoff0, &Bs[0][t*8]);
  async_cp16(Bbase + aoff1, &Bs[0][(t+256)*8]);

  int cur = 0;
  for(int k0=0;k0<K;k0+=BK){
    __syncthreads();
    if(k0+BK < K){
      int nb = cur^1;
      async_cp16(Abase + (k0+BK) + aoff0, &As[nb][t*8]);
      async_cp16(Abase + (k0+BK) + aoff1, &As[nb][(t+256)*8]);
      async_cp16(Bbase + (k0+BK) + aoff0, &Bs[nb][t*8]);
      async_cp16(Bbase + (k0+BK) + aoff1, &Bs[nb][(t+256)*8]);
    }
    bf16x8 af[4], bfr[4];
    #pragma unroll
    for(int i=0;i<4;i++){
      int ra = wm*64 + i*16 + c;
      int qa = ((ra&1)*4 + g) ^ ((ra>>1)&7);
      af[i]  = *(const bf16x8*)(&As[cur][(ra>>1)*64 + qa*8]);
      int rb = wn*64 + i*16 + c;
      int qb = ((rb&1)*4 + g) ^ ((rb>>1)&7);
      bfr[i] = *(const bf16x8*)(&Bs[cur][(rb>>1)*64 + qb*8]);
    }
    #pragma unroll
    for(int mi=0;mi<4;mi++)
      #pragma unroll
      for(int ni=0;ni<4;ni++)
        acc[mi][ni] = __builtin_amdgcn_mfma_f32_16x16x32_bf16(af[mi], bfr[ni], acc[mi][ni], 0,0,0);
    cur ^= 1;
  }
  if(MODE==1){
    #pragma unroll
    for(int mi=0;mi<4;mi++){
      int mrow = m0 + wm*64 + mi*16 + g*4;
      #pragma unroll
      for(int ni=0;ni<4;ni++){
        int ncol = n0 + wn*64 + ni*16 + c;
        #pragma unroll
        for(int r=0;r<4;r++)
          outf[(size_t)(mrow+r)*N + ncol] = acc[mi][ni][r];
      }
    }
  } else {
    #pragma unroll
    for(int ni=0;ni<4;ni++){
      int n = n0 + wn*64 + ni*16 + c;
      int sel = n>>10, head = (n>>6)&15, d = n&63;
      #pragma unroll
      for(int mi=0;mi<4;mi++){
        int m = m0 + wm*64 + mi*16 + g*4;
        int b = m>>11, l = m&(SEQ-1);
        if(sel<2){
          u16* dst = (sel==0?Qb:Kb) + ((size_t)((b*NHEADS+head)*SEQ + l))*DHEAD + d;
          #pragma unroll
          for(int r=0;r<4;r++) dst[(size_t)r*DHEAD] = f2bf(acc[mi][ni][r]);
        } else {
          ushort4 pk;
          pk.x=f2bf(acc[mi][ni][0]); pk.y=f2bf(acc[mi][ni][1]);
          pk.z=f2bf(acc[mi][ni][2]); pk.w=f2bf(acc[mi][ni][3]);
          *(ushort4*)(&Vtb[((size_t)((b*NHEADS+head)*DHEAD + d))*SEQ + l]) = pk;
        }
      }
    }
  }
}

// ---------------- RoPE: one thread per (l,j), sincos once, loop over bh ----------------
// Q additionally pre-scaled by scale*log2(e) so attn's softmax is a bare exp2.
#define SC2 0.180336879f   // 0.125 * log2(e)
__global__ __launch_bounds__(256) void rope_kernel(u16* __restrict__ Q, u16* __restrict__ Kb){
  int tid = blockIdx.x*256 + threadIdx.x;   // SEQ*32 threads
  int j = tid&31, l = tid>>5;
  float inv = exp2f(-(float)j * (13.28771237954945f/32.0f)); // 10000^(-j/32)
  float sn, cs;
  sincosf((float)l*inv, &sn, &cs);
  size_t base = (size_t)l*DHEAD + 2*j;
  #pragma unroll 4
  for(int bh=0; bh<BHTOT; bh++){
    size_t off = base + (size_t)bh*SEQ*DHEAD;
    ushort2 q2 = *(ushort2*)(&Q[off]);
    float x1=bf2f(q2.x), x2=bf2f(q2.y);
    ushort2 o;
    o.x = f2bf((x1*cs - x2*sn)*SC2); o.y = f2bf((x1*sn + x2*cs)*SC2);
    *(ushort2*)(&Q[off]) = o;
    ushort2 k2 = *(ushort2*)(&Kb[off]);
    x1=bf2f(k2.x); x2=bf2f(k2.y);
    o.x = f2bf(x1*cs - x2*sn); o.y = f2bf(x1*sn + x2*cs);
    *(ushort2*)(&Kb[off]) = o;
  }
}

// ---------------- Flash attention: 8-wave LDS-shared K/V, balanced strip-pairs ----------------
// Block = 512 threads (8 waves), grid (64 bh x 4 y-groups) = 256 blocks.
// Wave w owns TWO q-strips: sA = 8y+w and sB = 63-8y-w -> per-wave compute =
// (sA+1)+(sB+1) = 65 tiles, uniform across ALL waves and blocks (perfect balance).
// The block's double-buffered LDS K/V stream (tiles 0..NT-1, NT=64-8y) feeds both
// units off the SAME kf/vf reads: 2x compute per barrier and per ds_read.
// Staging: global_load_lds 16B, waves 0-3 stage K, 4-7 stage V, pre-swizzled
// source (rule 21), chunk j ^= pair-row&7 -> conflict-free reads.
// Per unit: S^T = mfma32x32x16(K,Q); P->bf16 A-frags in registers (cvt_pk +
// permlane32_swap, T12); 8 MFMA/unit. Row-sum in VALU on live exp values.

#define QKS32(QF) { \
  f32x16 z_ = {}; \
  z_ = __builtin_amdgcn_mfma_f32_32x32x16_bf16(kf[0], QF[0], z_, 0,0,0); \
  z_ = __builtin_amdgcn_mfma_f32_32x32x16_bf16(kf[1], QF[1], z_, 0,0,0); \
  z_ = __builtin_amdgcn_mfma_f32_32x32x16_bf16(kf[2], QF[2], z_, 0,0,0); \
  z_ = __builtin_amdgcn_mfma_f32_32x32x16_bf16(kf[3], QF[3], z_, 0,0,0); \
  sc = z_; }

// LDS reads with the tile swizzle (addresses stay 16B-aligned: only bits 4-6 flip)
#define LDK { \
  _Pragma("unroll") for(int dk_=0;dk_<4;dk_++){ \
    int kb_ = (c32*128 + dk_*32 + hl*16) ^ ((c32&7)<<4); \
    kf[dk_] = *(const bf16x8*)((const char*)(&Kls[cur][0]) + kb_); } }

#define LDV { \
  _Pragma("unroll") for(int dt_=0;dt_<2;dt_++) \
    _Pragma("unroll") for(int ks_=0;ks_<2;ks_++){ \
      int d_ = dt_*32 + c32; \
      int vb_ = (d_*64 + ks_*32 + hl*16) ^ (((d_>>1)&7)<<4); \
      vf[dt_][ks_] = *(const bf16x8*)((const char*)(&Vls[cur][0]) + vb_); } }

// pk_[j] = packed bf16 of P for regs (2j,2j+1); after the swaps, pk words are the
// PV A-frag words (k = 8*hl + elem). LROW accumulates this lane's half-row sum.
#define EXPPACK(MASKED, LROW) { \
  unsigned int pk_[8]; \
  _Pragma("unroll") for(int j_=0;j_<8;j_++){ \
    float a_ = exp2f(sc[2*j_]); \
    float b_ = exp2f(sc[2*j_+1]); \
    if(MASKED){ \
      int k0_ = ((2*j_)&3)   + 8*((2*j_)>>2)   + 4*hl; \
      int k1_ = ((2*j_+1)&3) + 8*((2*j_+1)>>2) + 4*hl; \
      a_ = (k0_ <= c32) ? a_ : 0.f; \
      b_ = (k1_ <= c32) ? b_ : 0.f; } \
    LROW += a_ + b_; \
    asm("v_cvt_pk_bf16_f32 %0, %1, %2" : "=v"(pk_[j_]) : "v"(a_), "v"(b_)); } \
  plswap(pk_[0], pk_[2]); \
  plswap(pk_[1], pk_[3]); \
  plswap(pk_[4], pk_[6]); \
  plswap(pk_[5], pk_[7]); \
  u32x4 wa_ = { pk_[0], pk_[1], pk_[2], pk_[3] }; \
  u32x4 wb_ = { pk_[4], pk_[5], pk_[6], pk_[7] }; \
  pa0 = __builtin_bit_cast(bf16x8, wa_); \
  pa1 = __builtin_bit_cast(bf16x8, wb_); }

#define PVM32(O0, O1) { \
  O0 = __builtin_amdgcn_mfma_f32_32x32x16_bf16(pa0, vf[0][0], O0, 0,0,0); \
  O0 = __builtin_amdgcn_mfma_f32_32x32x16_bf16(pa1, vf[0][1], O0, 0,0,0); \
  O1 = __builtin_amdgcn_mfma_f32_32x32x16_bf16(pa0, vf[1][0], O1, 0,0,0); \
  O1 = __builtin_amdgcn_mfma_f32_32x32x16_bf16(pa1, vf[1][1], O1, 0,0,0); }

__global__ __launch_bounds__(512, 2) void attn_kernel(const u16* __restrict__ Q, const u16* __restrict__ Kb,
    const u16* __restrict__ Vt, u16* __restrict__ O){
  __shared__ u16 Kls[2][2048];   // K tile [32 rows][64 d], swizzle-stored
  __shared__ u16 Vls[2][2048];   // Vt tile [64 d][32 l], swizzle-stored
  __shared__ float LsA[8][32];   // per-wave row sums, strip A
  __shared__ float LsB[8][32];   // per-wave row sums, strip B
  int t = threadIdx.x, lane = t&63, w = t>>6;
  int c32 = lane&31, hl = lane>>5, h8 = hl*8;
  int bh = blockIdx.x;
  int b = bh>>4, hh = bh&15;
  int y = blockIdx.y;            // 0..3; y=0 dispatched first = longest (NT=64)
  int sA = 8*y + w;              // 0..31
  int sB = 63 - 8*y - w;         // 32..63  (sA < sB always; per-wave work = 65 tiles)
  int NT = 64 - 8*y;             // block stages tiles 0..NT-1 (covers sB of w=0)
  const u16* Qp = Q  + (size_t)bh*SEQ*DHEAD;
  const u16* Kp = Kb + (size_t)bh*SEQ*DHEAD;
  const u16* Vp = Vt + (size_t)bh*DHEAD*SEQ;

  // ---- staging role: waves 0-3 stage K (chunks 0..255), waves 4-7 stage V ----
  bool isK = (w < 4);
  int cch = isK ? t : (t - 256);   // 0..255
  int prow = cch>>3;
  int jsrc = (cch&7) ^ (prow&7);
  size_t soff0, sstep;
  if(isK){
    soff0 = (size_t)prow*64 + (size_t)jsrc*8;
    sstep = 32*64;
  } else {
    int c2 = prow*8 + jsrc;
    soff0 = (size_t)(c2>>2)*SEQ + (size_t)(c2&3)*8;
    sstep = 32;
  }
  const u16* sbase = isK ? Kp : Vp;

  // Q as B-frags for both strips: lane holds Q[wrow + c32][dk*16 + h8 .. +7]
  bf16x8 qfA[4], qfB[4];
  #pragma unroll
  for(int dk=0;dk<4;dk++){
    qfA[dk] = *(const bf16x8*)(&Qp[(size_t)(sA*32 + c32)*DHEAD + dk*16 + h8]);
    qfB[dk] = *(const bf16x8*)(&Qp[(size_t)(sB*32 + c32)*DHEAD + dk*16 + h8]);
  }

  f32x16 oaccA0 = {}, oaccA1 = {}, oaccB0 = {}, oaccB1 = {};
  float lrowA = 0.f, lrowB = 0.f;
  f32x16 sc;
  bf16x8 kf[4], vf[2][2], pa0, pa1;

  // prologue: stage tile 0 into buf 0
  {
    u16* dst = isK ? &Kls[0][cch*8] : &Vls[0][cch*8];
    async_cp16(sbase + soff0, dst);
  }
  int cur = 0;
  #pragma unroll 1
  for(int tt=0; tt<NT; ++tt){
    __syncthreads();               // drains vmcnt (staging) + barrier
    if(tt+1 < NT){
      u16* dst = isK ? &Kls[cur^1][cch*8] : &Vls[cur^1][cch*8];
      async_cp16(sbase + soff0 + (size_t)(tt+1)*sstep, dst);
    }
    if(tt <= sB){
      LDK; LDV;
      QKS32(qfB);
      if(tt == sB){ EXPPACK(1, lrowB); } else { EXPPACK(0, lrowB); }
      PVM32(oaccB0, oaccB1);
      if(tt <= sA){
        QKS32(qfA);
        if(tt == sA){ EXPPACK(1, lrowA); } else { EXPPACK(0, lrowA); }
        PVM32(oaccA0, oaccA1);
      }
    }
    cur ^= 1;
  }

  // ---- epilogue: combine k-half sums, broadcast via tiny LDS, write both strips ----
  float lrA = lrowA + __shfl_xor(lrowA, 32);
  float lrB = lrowB + __shfl_xor(lrowB, 32);
  __syncthreads();
  if(hl==0){ LsA[w][c32] = lrA; LsB[w][c32] = lrB; }
  __syncthreads();
  #pragma unroll
  for(int r=0;r<16;r++){
    int row = (r&3)+8*(r>>2)+4*hl;
    float livA = 1.0f/LsA[w][row];
    float livB = 1.0f/LsB[w][row];
    size_t oA = ((size_t)(b*SEQ + sA*32 + row))*DMODEL + hh*DHEAD;
    size_t oB = ((size_t)(b*SEQ + sB*32 + row))*DMODEL + hh*DHEAD;
    O[oA + c32]      = f2bf(oaccA0[r]*livA);
    O[oA + 32 + c32] = f2bf(oaccA1[r]*livA);
    O[oB + c32]      = f2bf(oaccB0[r]*livB);
    O[oB + 32 + c32] = f2bf(oaccB1[r]*livB);
  }
}

// ---------------- launch ----------------
extern "C" void kernel_launch(void* const* d_in, const int* in_sizes, int n_in,
                              void* d_out, int out_size, void* d_ws, size_t ws_size,
                              hipStream_t stream){
  const float* x    = (const float*)d_in[0];
  const float* W_in = (const float*)d_in[1];
  const float* W_o  = (const float*)d_in[2];
  u16* ws = (u16*)d_ws;
  const size_t T16 = (size_t)8*1024*1024;  // 8M bf16 elems = 16 MB per tensor
  u16* h   = ws;            // [8192][1024] bf16
  u16* Qb  = ws +   T16;    // [64][2048][64]
  u16* Kb  = ws + 2*T16;    // [64][2048][64]
  u16* Vtb = ws + 3*T16;    // [64][64][2048]  (V transposed)
  u16* Wb  = ws + 4*T16;    // W_in bf16 [3072][1024]
  u16* Wob = Wb + (size_t)3*DMODEL*DMODEL; // W_o bf16 [1024][1024]
  u16* Ob  = h;             // reuse: h dead after gemm1
  float* out = (float*)d_out;

  const int na4 = 3*DMODEL*DMODEL/4;  // W_in float4 count
  const int nb4 = DMODEL*DMODEL/4;
  cast2_kernel<<<dim3((na4+nb4)/256), dim3(256), 0, stream>>>(W_in, Wb, W_o, Wob, na4);
  ln_kernel<<<dim3(MROWS), dim3(256), 0, stream>>>(x, h);
  gemm_bt<0><<<dim3(3*DMODEL/BN, MROWS/BM), dim3(256), 0, stream>>>(
      h, Wb, Qb, Kb, Vtb, nullptr, MROWS, 3*DMODEL, DMODEL);
  rope_kernel<<<dim3(SEQ*32/256), dim3(256), 0, stream>>>(Qb, Kb);
  attn_kernel<<<dim3(BHTOT, 4), dim3(512), 0, stream>>>(Qb, Kb, Vtb, Ob);
  gemm_bt<1><<<dim3(DMODEL/BN, MROWS/BM), dim3(256), 0, stream>>>(
      Ob, Wob, nullptr, nullptr, nullptr, out, MROWS, DMODEL, DMODEL);
}